// Round 10
// baseline (1580.007 us; speedup 1.0000x reference)
//
#include <hip/hip_runtime.h>
#include <hip/hip_bf16.h>
#include <math.h>

#define NN 50000     // nodes
#define NE 400000    // edges
#define HH 4         // heads
#define CC 64        // per-head dim
#define HC 256       // H*C
#define GG 64        // graphs

// ---------------- encoder: h0 = relu(x @ enc_w + enc_b), [N,8]x[8,64] ----------------
__global__ __launch_bounds__(256) void encoder_kernel(
    const float* __restrict__ x, const float* __restrict__ w,
    const float* __restrict__ b, float* __restrict__ h0) {
  int idx = blockIdx.x * 256 + threadIdx.x;   // N*64 threads
  int node = idx >> 6, col = idx & 63;
  const float* xr = x + node * 8;
  float acc = b[col];
#pragma unroll
  for (int k = 0; k < 8; ++k) acc += xr[k] * w[k * 64 + col];
  h0[idx] = fmaxf(acc, 0.f);
}

// ---------------- no-LDS register-blocked matmul: out[M,256] = A[M,K]@W[K,256] ----
// Block: 32 rows x 256 cols. Thread: 8 rows x 4 cols (rows rg+4*i, rg=tid&3).
// A read DIRECTLY from global: per instruction a wave hits only 4 unique 16B
// addresses (lanes sharing rg broadcast) -> per-block A tile (32KB) re-read 4x
// via L1/L2 (~6us total L2 traffic). No LDS port pressure, no __syncthreads,
// occupancy VGPR-bound only (~20 waves/CU vs 9 with the LDS-staged variant).
// FMA accumulation order identical to the staged version -> bit-exact.
template <int K>
__global__ __launch_bounds__(256) void matmul_rb_kernel(
    const float* __restrict__ A, const float* __restrict__ W,
    const float* __restrict__ bias, float* __restrict__ out, int M) {
  const int tid = threadIdx.x;
  const int rg = tid & 3;
  const int cg = tid >> 2;
  const int r0 = blockIdx.x * 32;

  // per-thread row offsets (clamped for the tail block; stores are guarded)
  size_t rowoff[8];
#pragma unroll
  for (int i = 0; i < 8; ++i) {
    int row = r0 + rg + 4 * i;
    if (row >= M) row = M - 1;
    rowoff[i] = (size_t)row * K;
  }

  float bv0 = bias ? bias[cg * 4 + 0] : 0.f;
  float bv1 = bias ? bias[cg * 4 + 1] : 0.f;
  float bv2 = bias ? bias[cg * 4 + 2] : 0.f;
  float bv3 = bias ? bias[cg * 4 + 3] : 0.f;
  float acc[8][4];
#pragma unroll
  for (int i = 0; i < 8; ++i) {
    acc[i][0] = bv0; acc[i][1] = bv1; acc[i][2] = bv2; acc[i][3] = bv3;
  }

  const float* Wp = W + cg * 4;
  for (int k0 = 0; k0 < K; k0 += 4) {
    float4 w0 = *(const float4*)&Wp[(k0 + 0) * 256];
    float4 w1 = *(const float4*)&Wp[(k0 + 1) * 256];
    float4 w2 = *(const float4*)&Wp[(k0 + 2) * 256];
    float4 w3 = *(const float4*)&Wp[(k0 + 3) * 256];
#pragma unroll
    for (int i = 0; i < 8; ++i) {
      float4 a = *(const float4*)&A[rowoff[i] + k0];
      acc[i][0] += a.x * w0.x; acc[i][0] += a.y * w1.x;
      acc[i][0] += a.z * w2.x; acc[i][0] += a.w * w3.x;
      acc[i][1] += a.x * w0.y; acc[i][1] += a.y * w1.y;
      acc[i][1] += a.z * w2.y; acc[i][1] += a.w * w3.y;
      acc[i][2] += a.x * w0.z; acc[i][2] += a.y * w1.z;
      acc[i][2] += a.z * w2.z; acc[i][2] += a.w * w3.z;
      acc[i][3] += a.x * w0.w; acc[i][3] += a.y * w1.w;
      acc[i][3] += a.z * w2.w; acc[i][3] += a.w * w3.w;
    }
  }

#pragma unroll
  for (int i = 0; i < 8; ++i) {
    int row = r0 + rg + 4 * i;
    if (row < M) {
      float4 o = make_float4(acc[i][0], acc[i][1], acc[i][2], acc[i][3]);
      *(float4*)&out[(size_t)row * 256 + cg * 4] = o;
    }
  }
}

// ---------------- CSR build ----------------
__global__ void degree_kernel(const int* __restrict__ ei, int* __restrict__ deg) {
  int e = blockIdx.x * 256 + threadIdx.x;
  if (e < NE) atomicAdd(&deg[ei[NE + e]], 1);
}

__global__ __launch_bounds__(1024) void scan_kernel(
    const int* __restrict__ deg, int* __restrict__ rowstart) {
  __shared__ int buf0[1024];
  __shared__ int buf1[1024];
  int tid = threadIdx.x;
  const int per = (NN + 1023) / 1024;  // 49
  int s = tid * per, e = s + per; if (e > NN) e = NN; if (s > NN) s = NN;
  int sum = 0;
  for (int i = s; i < e; ++i) sum += deg[i];
  buf0[tid] = sum;
  __syncthreads();
  int* in = buf0; int* outb = buf1;
  for (int off = 1; off < 1024; off <<= 1) {
    int v = in[tid];
    if (tid >= off) v += in[tid - off];
    outb[tid] = v;
    __syncthreads();
    int* t = in; in = outb; outb = t;
  }
  int excl = in[tid] - sum;
  int run = excl;
  for (int i = s; i < e; ++i) { rowstart[i] = run; run += deg[i]; }
  if (tid == 1023) rowstart[NN] = in[1023];
}

__global__ void cursor_copy_kernel(const int* __restrict__ rowstart, int* __restrict__ cursor) {
  int i = blockIdx.x * 256 + threadIdx.x;
  if (i < NN) cursor[i] = rowstart[i];
}

// CSR fill: also materialize src and edge_attr in CSR order.
__global__ void fill_kernel(const int* __restrict__ ei, const float* __restrict__ ea,
                            int* __restrict__ cursor,
                            int* __restrict__ src_sorted, float* __restrict__ ea_sorted) {
  int e = blockIdx.x * 256 + threadIdx.x;
  if (e < NE) {
    int d = ei[NE + e];
    int pos = atomicAdd(&cursor[d], 1);
    src_sorted[pos] = ei[e];
    ea_sorted[pos] = ea[e];
  }
}

// ---------------- fused GATv2 edge phase: wave per dst node ----------------
__global__ __launch_bounds__(256) void gat_fused_kernel(
    const int* __restrict__ rowstart, const int* __restrict__ src_sorted,
    const float* __restrict__ ea_sorted,
    const float* __restrict__ xl, const float* __restrict__ xr,
    const float* __restrict__ we, const float* __restrict__ att,
    const float* __restrict__ bias, float* __restrict__ out) {
  int node = (blockIdx.x * 256 + threadIdx.x) >> 6;
  int lane = threadIdx.x & 63;
  int r0 = rowstart[node], r1 = rowstart[node + 1];
  const float4* xl4 = (const float4*)xl;
  float4 r = ((const float4*)xr)[node * 64 + lane];
  float4 wv = ((const float4*)we)[lane];
  float4 at = ((const float4*)att)[lane];
  float4 acc = make_float4(0.f, 0.f, 0.f, 0.f);
  float denom = 0.f;

  auto edge_step = [&](float eav, float4 a) {
    float s0 = a.x + r.x + eav * wv.x;
    float s1 = a.y + r.y + eav * wv.y;
    float s2 = a.z + r.z + eav * wv.z;
    float s3 = a.w + r.w + eav * wv.w;
    s0 = s0 > 0.f ? s0 : 0.2f * s0;
    s1 = s1 > 0.f ? s1 : 0.2f * s1;
    s2 = s2 > 0.f ? s2 : 0.2f * s2;
    s3 = s3 > 0.f ? s3 : 0.2f * s3;
    float p = s0 * at.x + s1 * at.y + s2 * at.z + s3 * at.w;
#pragma unroll
    for (int off = 8; off; off >>= 1) p += __shfl_xor(p, off, 16);
    float ex = __expf(p);
    denom += ex;
    acc.x += ex * a.x; acc.y += ex * a.y; acc.z += ex * a.z; acc.w += ex * a.w;
  };

  int i = r0;
  for (; i + 2 <= r1; i += 2) {           // pairwise: 2 gathers in flight
    int s0i = src_sorted[i];
    int s1i = src_sorted[i + 1];
    float e0 = ea_sorted[i];
    float e1 = ea_sorted[i + 1];
    float4 a0 = xl4[(size_t)s0i * 64 + lane];
    float4 a1 = xl4[(size_t)s1i * 64 + lane];
    edge_step(e0, a0);
    edge_step(e1, a1);
  }
  if (i < r1) {
    int s0i = src_sorted[i];
    float e0 = ea_sorted[i];
    float4 a0 = xl4[(size_t)s0i * 64 + lane];
    edge_step(e0, a0);
  }

  float inv = 1.f / (denom + 1e-16f);
  float4 bv = ((const float4*)bias)[lane];
  float4 o;
  o.x = fmaxf(acc.x * inv + bv.x, 0.f);
  o.y = fmaxf(acc.y * inv + bv.y, 0.f);
  o.z = fmaxf(acc.z * inv + bv.z, 0.f);
  o.w = fmaxf(acc.w * inv + bv.w, 0.f);
  ((float4*)out)[(size_t)node * 64 + lane] = o;
}

// ---------------- segment bounds via binary search (batch is sorted) ----------------
__global__ void seg_bounds_kernel(const int* __restrict__ batch, int* __restrict__ bounds) {
  int g = threadIdx.x;                 // 0..GG inclusive
  if (g > GG) return;
  int lo = 0, hi = NN;
  while (lo < hi) {                    // first index with batch[i] >= g
    int mid = (lo + hi) >> 1;
    if (batch[mid] < g) lo = mid + 1; else hi = mid;
  }
  bounds[g] = lo;
}

__global__ __launch_bounds__(256) void pool_kernel(
    const float* __restrict__ h, const int* __restrict__ batch,
    float* __restrict__ pool) {
  int start = blockIdx.x * 256;
  int end = start + 256; if (end > NN) end = NN;
  int tid = threadIdx.x;
  int cur = batch[start];
  float acc = 0.f;
  for (int n = start; n < end; ++n) {
    int b = batch[n];
    if (b != cur) {
      atomicAdd(&pool[cur * 256 + tid], acc);
      acc = 0.f; cur = b;
    }
    acc += h[n * 256 + tid];
  }
  atomicAdd(&pool[cur * 256 + tid], acc);
}

// ---------------- final MLP: one block (128 thr) per graph ----------------
__global__ __launch_bounds__(128) void mlp_kernel(
    const float* __restrict__ pool, const int* __restrict__ bounds,
    const float* __restrict__ p1w, const float* __restrict__ p1b,
    const float* __restrict__ lng, const float* __restrict__ lnb,
    const float* __restrict__ p2w, const float* __restrict__ p2b,
    const float* __restrict__ hw, const float* __restrict__ hb,
    float* __restrict__ out) {
  __shared__ float sg[256];
  __shared__ float red[128];
  __shared__ float sz[128];
  __shared__ float s2[64];
  int b = blockIdx.x, tid = threadIdx.x;
  float cntf = (float)(bounds[b + 1] - bounds[b]);
  float invc = 1.f / fmaxf(cntf, 1.f);
  for (int i = tid; i < 256; i += 128) sg[i] = pool[b * 256 + i] * invc;
  __syncthreads();
  float z = p1b[tid];
  for (int k = 0; k < 256; ++k) z += sg[k] * p1w[k * 128 + tid];
  red[tid] = z; __syncthreads();
  for (int off = 64; off; off >>= 1) { if (tid < off) red[tid] += red[tid + off]; __syncthreads(); }
  float mu = red[0] * (1.f / 128.f);
  __syncthreads();
  float d = z - mu;
  red[tid] = d * d; __syncthreads();
  for (int off = 64; off; off >>= 1) { if (tid < off) red[tid] += red[tid + off]; __syncthreads(); }
  float var = red[0] * (1.f / 128.f);
  float zn = d * rsqrtf(var + 1e-5f) * lng[tid] + lnb[tid];
  sz[tid] = fmaxf(zn, 0.f);
  __syncthreads();
  if (tid < 64) {
    float a = p2b[tid];
    for (int k = 0; k < 128; ++k) a += sz[k] * p2w[k * 64 + tid];
    s2[tid] = fmaxf(a, 0.f);
  }
  __syncthreads();
  if (tid < 64) {
    float p = s2[tid] * hw[tid];
    for (int off = 32; off; off >>= 1) p += __shfl_down(p, off, 64);
    if (tid == 0) out[b] = p + hb[0];
  }
}

extern "C" void kernel_launch(void* const* d_in, const int* in_sizes, int n_in,
                              void* d_out, int out_size, void* d_ws, size_t ws_size,
                              hipStream_t stream) {
  const float* x      = (const float*)d_in[0];
  const int*   ei     = (const int*)d_in[1];
  const float* ea     = (const float*)d_in[2];
  const int*   batch  = (const int*)d_in[3];
  const float* enc_w  = (const float*)d_in[4];
  const float* enc_b  = (const float*)d_in[5];
  const float* g1_wl  = (const float*)d_in[6];
  const float* g1_bl  = (const float*)d_in[7];
  const float* g1_wr  = (const float*)d_in[8];
  const float* g1_we  = (const float*)d_in[9];
  const float* g1_att = (const float*)d_in[10];
  const float* g1_b   = (const float*)d_in[11];
  const float* g2_wl  = (const float*)d_in[12];
  const float* g2_bl  = (const float*)d_in[13];
  const float* g2_wr  = (const float*)d_in[14];
  const float* g2_we  = (const float*)d_in[15];
  const float* g2_att = (const float*)d_in[16];
  const float* g2_b   = (const float*)d_in[17];
  const float* p1_w   = (const float*)d_in[18];
  const float* p1_b   = (const float*)d_in[19];
  const float* ln_g   = (const float*)d_in[20];
  const float* ln_b   = (const float*)d_in[21];
  const float* p2_w   = (const float*)d_in[22];
  const float* p2_b   = (const float*)d_in[23];
  const float* head_w = (const float*)d_in[24];
  const float* head_b = (const float*)d_in[25];
  float* out = (float*)d_out;

  char* ws = (char*)d_ws;
  size_t off = 0;
  auto alloc = [&](size_t bytes) -> void* {
    void* p = ws + off;
    off = (off + bytes + 255) & ~(size_t)255;
    return p;
  };
  float* h0        = (float*)alloc((size_t)NN * 64 * 4);
  float* hbuf      = (float*)alloc((size_t)NN * HC * 4);
  float* xl        = (float*)alloc((size_t)NN * HC * 4);
  float* xr        = (float*)alloc((size_t)NN * HC * 4);
  float* pool      = (float*)alloc((size_t)GG * HC * 4);
  int*   deg       = (int*)alloc((size_t)NN * 4);
  int*   rowstart  = (int*)alloc((size_t)(NN + 1) * 4);
  int*   cursor    = (int*)alloc((size_t)NN * 4);
  int*   src_sorted= (int*)alloc((size_t)NE * 4);
  float* ea_sorted = (float*)alloc((size_t)NE * 4);
  int*   bounds    = (int*)alloc((size_t)(GG + 1) * 4);

  hipMemsetAsync(deg, 0, (size_t)NN * 4, stream);
  hipMemsetAsync(pool, 0, (size_t)GG * HC * 4, stream);

  // encoder
  encoder_kernel<<<NN * 64 / 256, 256, 0, stream>>>(x, enc_w, enc_b, h0);

  // CSR build (shared by both layers)
  degree_kernel<<<(NE + 255) / 256, 256, 0, stream>>>(ei, deg);
  scan_kernel<<<1, 1024, 0, stream>>>(deg, rowstart);
  cursor_copy_kernel<<<(NN + 255) / 256, 256, 0, stream>>>(rowstart, cursor);
  fill_kernel<<<(NE + 255) / 256, 256, 0, stream>>>(ei, ea, cursor, src_sorted, ea_sorted);

  // graph segment bounds (batch is sorted)
  seg_bounds_kernel<<<1, GG + 1, 0, stream>>>(batch, bounds);

  const int MMB = (NN + 31) / 32;  // matmul blocks

  // ---- GAT layer 1 (K=64) ----
  matmul_rb_kernel<64><<<MMB, 256, 0, stream>>>(h0, g1_wl, g1_bl, xl, NN);
  matmul_rb_kernel<64><<<MMB, 256, 0, stream>>>(h0, g1_wr, nullptr, xr, NN);
  gat_fused_kernel<<<NN / 4, 256, 0, stream>>>(rowstart, src_sorted, ea_sorted,
                                               xl, xr, g1_we, g1_att, g1_b, hbuf);

  // ---- GAT layer 2 (K=256) ----
  matmul_rb_kernel<256><<<MMB, 256, 0, stream>>>(hbuf, g2_wl, g2_bl, xl, NN);
  matmul_rb_kernel<256><<<MMB, 256, 0, stream>>>(hbuf, g2_wr, nullptr, xr, NN);
  gat_fused_kernel<<<NN / 4, 256, 0, stream>>>(rowstart, src_sorted, ea_sorted,
                                               xl, xr, g2_we, g2_att, g2_b, hbuf);

  // ---- pooling + MLP head ----
  pool_kernel<<<(NN + 255) / 256, 256, 0, stream>>>(hbuf, batch, pool);
  mlp_kernel<<<GG, 128, 0, stream>>>(pool, bounds, p1_w, p1_b, ln_g, ln_b,
                                     p2_w, p2_b, head_w, head_b, out);
}

// Round 11
// 563.338 us; speedup vs baseline: 2.8047x; 2.8047x over previous
//
#include <hip/hip_runtime.h>
#include <hip/hip_bf16.h>
#include <math.h>

#define NN 50000     // nodes
#define NE 400000    // edges
#define HH 4         // heads
#define CC 64        // per-head dim
#define HC 256       // H*C
#define GG 64        // graphs

typedef short v8s __attribute__((ext_vector_type(8)));
typedef float f32x4 __attribute__((ext_vector_type(4)));

static __device__ inline unsigned short f2bf(float v) {
  __hip_bfloat16 b = __float2bfloat16(v);
  return *reinterpret_cast<unsigned short*>(&b);
}
static __device__ inline float bf2f(unsigned short u) {
  __hip_bfloat16 b = *reinterpret_cast<__hip_bfloat16*>(&u);
  return __bfloat162float(b);
}
static __device__ inline void bf16split(float v, unsigned short& h, unsigned short& l) {
  h = f2bf(v);
  l = f2bf(v - bf2f(h));
}

// ---------------- encoder: h0 = relu(x @ enc_w + enc_b) -> bf16 ----------------
__global__ __launch_bounds__(256) void encoder_kernel(
    const float* __restrict__ x, const float* __restrict__ w,
    const float* __restrict__ b, unsigned short* __restrict__ h0) {
  int idx = blockIdx.x * 256 + threadIdx.x;   // N*64 threads
  int node = idx >> 6, col = idx & 63;
  const float* xr = x + node * 8;
  float acc = b[col];
#pragma unroll
  for (int k = 0; k < 8; ++k) acc += xr[k] * w[k * 64 + col];
  h0[idx] = f2bf(fmaxf(acc, 0.f));
}

// ---- W prep: W[K,256] f32 -> Wt hi/lo bf16 [256][K] (k-contiguous rows) ----
__global__ __launch_bounds__(256) void wconv_kernel(
    const float* __restrict__ W, int K,
    unsigned short* __restrict__ Wthi, unsigned short* __restrict__ Wtlo) {
  int idx = blockIdx.x * 256 + threadIdx.x;
  if (idx >= K * 256) return;
  int k = idx >> 8, n = idx & 255;
  unsigned short h, l;
  bf16split(W[idx], h, l);
  Wthi[n * K + k] = h;
  Wtlo[n * K + k] = l;
}

// ---------------- MFMA matmul: out[M,256] = A(bf16) @ (Whi+Wlo) (+bias) ----------------
// Block 128 rows x 128 cols, 4 waves (2x2), each wave 64x64 = 4x4 tiles of
// 16x16x32. LDS-staged A/Bhi/Blo chunks (k=32) -> ds_read_b128 fragment loads
// (round-8's un-staged global B scatter was the failure; the A/B/C lane mappings
// here are exactly the round-8 HW-verified ones). Split-W 2-MFMA: A*Wlo then
// A*Whi into the same f32 acc (W systematic rounding removed; A bf16 noise is
// per-node random and killed by the mean-pool).
template <int K, bool HAS_BIAS>
__global__ __launch_bounds__(256) void matmul_mfma_kernel(
    const unsigned short* __restrict__ A,
    const unsigned short* __restrict__ Wthi, const unsigned short* __restrict__ Wtlo,
    const float* __restrict__ bias, float* __restrict__ out, int M) {
  constexpr int AP = 40;                 // LDS k-stride (shorts): 80B, 16B-aligned, bank-spread
  __shared__ unsigned short a_lds[128 * AP];
  __shared__ unsigned short bh_lds[128 * AP];
  __shared__ unsigned short bl_lds[128 * AP];
  const int tid = threadIdx.x;
  const int wave = tid >> 6;
  const int lane = tid & 63;
  const int quad = lane >> 4;
  const int lrow = lane & 15;
  const int wr = (wave & 1) * 64;        // wave row offset in block
  const int wc = (wave >> 1) * 64;       // wave col offset in block
  const int r0 = blockIdx.x * 128;
  const int n0 = blockIdx.y * 128;

  f32x4 acc[4][4];
#pragma unroll
  for (int i = 0; i < 4; ++i)
#pragma unroll
    for (int j = 0; j < 4; ++j) acc[i][j] = (f32x4){0.f, 0.f, 0.f, 0.f};

  const int srow = tid >> 1;             // staging: 2 threads per row
  const int shalf = tid & 1;             // 16-short half of the 32-k chunk
  int agrow = r0 + srow; if (agrow >= M) agrow = M - 1;   // clamp; stores guarded
  const int bgrow = n0 + srow;           // 0..255, always valid

  for (int k0 = 0; k0 < K; k0 += 32) {
    {
      const float4* sa = (const float4*)&A[(size_t)agrow * K + k0 + shalf * 16];
      const float4* sh = (const float4*)&Wthi[(size_t)bgrow * K + k0 + shalf * 16];
      const float4* sl = (const float4*)&Wtlo[(size_t)bgrow * K + k0 + shalf * 16];
      float4 va0 = sa[0], va1 = sa[1];
      float4 vh0 = sh[0], vh1 = sh[1];
      float4 vl0 = sl[0], vl1 = sl[1];
      *(float4*)&a_lds[srow * AP + shalf * 16]      = va0;
      *(float4*)&a_lds[srow * AP + shalf * 16 + 8]  = va1;
      *(float4*)&bh_lds[srow * AP + shalf * 16]     = vh0;
      *(float4*)&bh_lds[srow * AP + shalf * 16 + 8] = vh1;
      *(float4*)&bl_lds[srow * AP + shalf * 16]     = vl0;
      *(float4*)&bl_lds[srow * AP + shalf * 16 + 8] = vl1;
    }
    __syncthreads();

    v8s af[4], bh[4], bl[4];
#pragma unroll
    for (int rt = 0; rt < 4; ++rt)
      af[rt] = *(const v8s*)&a_lds[(wr + rt * 16 + lrow) * AP + quad * 8];
#pragma unroll
    for (int ct = 0; ct < 4; ++ct) {
      bh[ct] = *(const v8s*)&bh_lds[(wc + ct * 16 + lrow) * AP + quad * 8];
      bl[ct] = *(const v8s*)&bl_lds[(wc + ct * 16 + lrow) * AP + quad * 8];
    }
#pragma unroll
    for (int rt = 0; rt < 4; ++rt)
#pragma unroll
      for (int ct = 0; ct < 4; ++ct) {
        acc[rt][ct] = __builtin_amdgcn_mfma_f32_16x16x32_bf16(af[rt], bl[ct], acc[rt][ct], 0, 0, 0);
        acc[rt][ct] = __builtin_amdgcn_mfma_f32_16x16x32_bf16(af[rt], bh[ct], acc[rt][ct], 0, 0, 0);
      }
    __syncthreads();
  }

#pragma unroll
  for (int rt = 0; rt < 4; ++rt) {
    int mbase = r0 + wr + rt * 16 + quad * 4;
#pragma unroll
    for (int ct = 0; ct < 4; ++ct) {
      int col = n0 + wc + ct * 16 + lrow;
      float b = HAS_BIAS ? bias[col] : 0.f;
#pragma unroll
      for (int r = 0; r < 4; ++r) {
        int row = mbase + r;
        if (row < M) out[(size_t)row * 256 + col] = acc[rt][ct][r] + b;
      }
    }
  }
}

// ---------------- CSR build ----------------
__global__ void degree_kernel(const int* __restrict__ ei, int* __restrict__ deg) {
  int e = blockIdx.x * 256 + threadIdx.x;
  if (e < NE) atomicAdd(&deg[ei[NE + e]], 1);
}

__global__ __launch_bounds__(1024) void scan_kernel(
    const int* __restrict__ deg, int* __restrict__ rowstart) {
  __shared__ int buf0[1024];
  __shared__ int buf1[1024];
  int tid = threadIdx.x;
  const int per = (NN + 1023) / 1024;  // 49
  int s = tid * per, e = s + per; if (e > NN) e = NN; if (s > NN) s = NN;
  int sum = 0;
  for (int i = s; i < e; ++i) sum += deg[i];
  buf0[tid] = sum;
  __syncthreads();
  int* in = buf0; int* outb = buf1;
  for (int off = 1; off < 1024; off <<= 1) {
    int v = in[tid];
    if (tid >= off) v += in[tid - off];
    outb[tid] = v;
    __syncthreads();
    int* t = in; in = outb; outb = t;
  }
  int excl = in[tid] - sum;
  int run = excl;
  for (int i = s; i < e; ++i) { rowstart[i] = run; run += deg[i]; }
  if (tid == 1023) rowstart[NN] = in[1023];
}

__global__ void cursor_copy_kernel(const int* __restrict__ rowstart, int* __restrict__ cursor) {
  int i = blockIdx.x * 256 + threadIdx.x;
  if (i < NN) cursor[i] = rowstart[i];
}

__global__ void fill_kernel(const int* __restrict__ ei, const float* __restrict__ ea,
                            int* __restrict__ cursor,
                            int* __restrict__ src_sorted, float* __restrict__ ea_sorted) {
  int e = blockIdx.x * 256 + threadIdx.x;
  if (e < NE) {
    int d = ei[NE + e];
    int pos = atomicAdd(&cursor[d], 1);
    src_sorted[pos] = ei[e];
    ea_sorted[pos] = ea[e];
  }
}

// ---------------- fused GATv2 edge phase: wave per dst node ----------------
// OUTBF=true: write relu(out) as packed bf16 (A operand of next MFMA matmul).
template <bool OUTBF>
__global__ __launch_bounds__(256) void gat_fused_kernel(
    const int* __restrict__ rowstart, const int* __restrict__ src_sorted,
    const float* __restrict__ ea_sorted,
    const float* __restrict__ xl, const float* __restrict__ xr,
    const float* __restrict__ we, const float* __restrict__ att,
    const float* __restrict__ bias, float* __restrict__ outf,
    unsigned short* __restrict__ outb) {
  int node = (blockIdx.x * 256 + threadIdx.x) >> 6;
  int lane = threadIdx.x & 63;
  int r0 = rowstart[node], r1 = rowstart[node + 1];
  const float4* xl4 = (const float4*)xl;
  float4 r = ((const float4*)xr)[node * 64 + lane];
  float4 wv = ((const float4*)we)[lane];
  float4 at = ((const float4*)att)[lane];
  float4 acc = make_float4(0.f, 0.f, 0.f, 0.f);
  float denom = 0.f;

  auto edge_step = [&](float eav, float4 a) {
    float s0 = a.x + r.x + eav * wv.x;
    float s1 = a.y + r.y + eav * wv.y;
    float s2 = a.z + r.z + eav * wv.z;
    float s3 = a.w + r.w + eav * wv.w;
    s0 = s0 > 0.f ? s0 : 0.2f * s0;
    s1 = s1 > 0.f ? s1 : 0.2f * s1;
    s2 = s2 > 0.f ? s2 : 0.2f * s2;
    s3 = s3 > 0.f ? s3 : 0.2f * s3;
    float p = s0 * at.x + s1 * at.y + s2 * at.z + s3 * at.w;
#pragma unroll
    for (int off = 8; off; off >>= 1) p += __shfl_xor(p, off, 16);
    float ex = __expf(p);
    denom += ex;
    acc.x += ex * a.x; acc.y += ex * a.y; acc.z += ex * a.z; acc.w += ex * a.w;
  };

  int i = r0;
  for (; i + 2 <= r1; i += 2) {           // pairwise: 2 gathers in flight
    int s0i = src_sorted[i];
    int s1i = src_sorted[i + 1];
    float e0 = ea_sorted[i];
    float e1 = ea_sorted[i + 1];
    float4 a0 = xl4[(size_t)s0i * 64 + lane];
    float4 a1 = xl4[(size_t)s1i * 64 + lane];
    edge_step(e0, a0);
    edge_step(e1, a1);
  }
  if (i < r1) {
    int s0i = src_sorted[i];
    float e0 = ea_sorted[i];
    float4 a0 = xl4[(size_t)s0i * 64 + lane];
    edge_step(e0, a0);
  }

  float inv = 1.f / (denom + 1e-16f);
  float4 bv = ((const float4*)bias)[lane];
  float4 o;
  o.x = fmaxf(acc.x * inv + bv.x, 0.f);
  o.y = fmaxf(acc.y * inv + bv.y, 0.f);
  o.z = fmaxf(acc.z * inv + bv.z, 0.f);
  o.w = fmaxf(acc.w * inv + bv.w, 0.f);
  if (OUTBF) {
    uint2 pk;
    pk.x = (unsigned)f2bf(o.x) | ((unsigned)f2bf(o.y) << 16);
    pk.y = (unsigned)f2bf(o.z) | ((unsigned)f2bf(o.w) << 16);
    ((uint2*)outb)[(size_t)node * 64 + lane] = pk;
  } else {
    ((float4*)outf)[(size_t)node * 64 + lane] = o;
  }
}

// ---------------- segment bounds via binary search (batch is sorted) ----------------
__global__ void seg_bounds_kernel(const int* __restrict__ batch, int* __restrict__ bounds) {
  int g = threadIdx.x;                 // 0..GG inclusive
  if (g > GG) return;
  int lo = 0, hi = NN;
  while (lo < hi) {
    int mid = (lo + hi) >> 1;
    if (batch[mid] < g) lo = mid + 1; else hi = mid;
  }
  bounds[g] = lo;
}

__global__ __launch_bounds__(256) void pool_kernel(
    const float* __restrict__ h, const int* __restrict__ batch,
    float* __restrict__ pool) {
  int start = blockIdx.x * 256;
  int end = start + 256; if (end > NN) end = NN;
  int tid = threadIdx.x;
  int cur = batch[start];
  float acc = 0.f;
  for (int n = start; n < end; ++n) {
    int b = batch[n];
    if (b != cur) {
      atomicAdd(&pool[cur * 256 + tid], acc);
      acc = 0.f; cur = b;
    }
    acc += h[n * 256 + tid];
  }
  atomicAdd(&pool[cur * 256 + tid], acc);
}

// ---------------- final MLP: one block (128 thr) per graph ----------------
__global__ __launch_bounds__(128) void mlp_kernel(
    const float* __restrict__ pool, const int* __restrict__ bounds,
    const float* __restrict__ p1w, const float* __restrict__ p1b,
    const float* __restrict__ lng, const float* __restrict__ lnb,
    const float* __restrict__ p2w, const float* __restrict__ p2b,
    const float* __restrict__ hw, const float* __restrict__ hb,
    float* __restrict__ out) {
  __shared__ float sg[256];
  __shared__ float red[128];
  __shared__ float sz[128];
  __shared__ float s2[64];
  int b = blockIdx.x, tid = threadIdx.x;
  float cntf = (float)(bounds[b + 1] - bounds[b]);
  float invc = 1.f / fmaxf(cntf, 1.f);
  for (int i = tid; i < 256; i += 128) sg[i] = pool[b * 256 + i] * invc;
  __syncthreads();
  float z = p1b[tid];
  for (int k = 0; k < 256; ++k) z += sg[k] * p1w[k * 128 + tid];
  red[tid] = z; __syncthreads();
  for (int off = 64; off; off >>= 1) { if (tid < off) red[tid] += red[tid + off]; __syncthreads(); }
  float mu = red[0] * (1.f / 128.f);
  __syncthreads();
  float d = z - mu;
  red[tid] = d * d; __syncthreads();
  for (int off = 64; off; off >>= 1) { if (tid < off) red[tid] += red[tid + off]; __syncthreads(); }
  float var = red[0] * (1.f / 128.f);
  float zn = d * rsqrtf(var + 1e-5f) * lng[tid] + lnb[tid];
  sz[tid] = fmaxf(zn, 0.f);
  __syncthreads();
  if (tid < 64) {
    float a = p2b[tid];
    for (int k = 0; k < 128; ++k) a += sz[k] * p2w[k * 64 + tid];
    s2[tid] = fmaxf(a, 0.f);
  }
  __syncthreads();
  if (tid < 64) {
    float p = s2[tid] * hw[tid];
    for (int off = 32; off; off >>= 1) p += __shfl_down(p, off, 64);
    if (tid == 0) out[b] = p + hb[0];
  }
}

extern "C" void kernel_launch(void* const* d_in, const int* in_sizes, int n_in,
                              void* d_out, int out_size, void* d_ws, size_t ws_size,
                              hipStream_t stream) {
  const float* x      = (const float*)d_in[0];
  const int*   ei     = (const int*)d_in[1];
  const float* ea     = (const float*)d_in[2];
  const int*   batch  = (const int*)d_in[3];
  const float* enc_w  = (const float*)d_in[4];
  const float* enc_b  = (const float*)d_in[5];
  const float* g1_wl  = (const float*)d_in[6];
  const float* g1_bl  = (const float*)d_in[7];
  const float* g1_wr  = (const float*)d_in[8];
  const float* g1_we  = (const float*)d_in[9];
  const float* g1_att = (const float*)d_in[10];
  const float* g1_b   = (const float*)d_in[11];
  const float* g2_wl  = (const float*)d_in[12];
  const float* g2_bl  = (const float*)d_in[13];
  const float* g2_wr  = (const float*)d_in[14];
  const float* g2_we  = (const float*)d_in[15];
  const float* g2_att = (const float*)d_in[16];
  const float* g2_b   = (const float*)d_in[17];
  const float* p1_w   = (const float*)d_in[18];
  const float* p1_b   = (const float*)d_in[19];
  const float* ln_g   = (const float*)d_in[20];
  const float* ln_b   = (const float*)d_in[21];
  const float* p2_w   = (const float*)d_in[22];
  const float* p2_b   = (const float*)d_in[23];
  const float* head_w = (const float*)d_in[24];
  const float* head_b = (const float*)d_in[25];
  float* out = (float*)d_out;

  char* ws = (char*)d_ws;
  size_t off = 0;
  auto alloc = [&](size_t bytes) -> void* {
    void* p = ws + off;
    off = (off + bytes + 255) & ~(size_t)255;
    return p;
  };
  float* xl        = (float*)alloc((size_t)NN * HC * 4);
  float* xr        = (float*)alloc((size_t)NN * HC * 4);
  float* hbuf      = (float*)alloc((size_t)NN * HC * 4);
  unsigned short* h0   = (unsigned short*)alloc((size_t)NN * 64 * 2);
  unsigned short* hb16 = (unsigned short*)alloc((size_t)NN * HC * 2);
  unsigned short* wt1l_hi = (unsigned short*)alloc((size_t)64 * 256 * 2);
  unsigned short* wt1l_lo = (unsigned short*)alloc((size_t)64 * 256 * 2);
  unsigned short* wt1r_hi = (unsigned short*)alloc((size_t)64 * 256 * 2);
  unsigned short* wt1r_lo = (unsigned short*)alloc((size_t)64 * 256 * 2);
  unsigned short* wt2l_hi = (unsigned short*)alloc((size_t)256 * 256 * 2);
  unsigned short* wt2l_lo = (unsigned short*)alloc((size_t)256 * 256 * 2);
  unsigned short* wt2r_hi = (unsigned short*)alloc((size_t)256 * 256 * 2);
  unsigned short* wt2r_lo = (unsigned short*)alloc((size_t)256 * 256 * 2);
  float* pool      = (float*)alloc((size_t)GG * HC * 4);
  int*   deg       = (int*)alloc((size_t)NN * 4);
  int*   rowstart  = (int*)alloc((size_t)(NN + 1) * 4);
  int*   cursor    = (int*)alloc((size_t)NN * 4);
  int*   src_sorted= (int*)alloc((size_t)NE * 4);
  float* ea_sorted = (float*)alloc((size_t)NE * 4);
  int*   bounds    = (int*)alloc((size_t)(GG + 1) * 4);

  hipMemsetAsync(deg, 0, (size_t)NN * 4, stream);
  hipMemsetAsync(pool, 0, (size_t)GG * HC * 4, stream);

  // encoder (bf16 out) + weight prep
  encoder_kernel<<<NN * 64 / 256, 256, 0, stream>>>(x, enc_w, enc_b, h0);
  wconv_kernel<<<64, 256, 0, stream>>>(g1_wl, 64, wt1l_hi, wt1l_lo);
  wconv_kernel<<<64, 256, 0, stream>>>(g1_wr, 64, wt1r_hi, wt1r_lo);
  wconv_kernel<<<256, 256, 0, stream>>>(g2_wl, 256, wt2l_hi, wt2l_lo);
  wconv_kernel<<<256, 256, 0, stream>>>(g2_wr, 256, wt2r_hi, wt2r_lo);

  // CSR build (shared by both layers)
  degree_kernel<<<(NE + 255) / 256, 256, 0, stream>>>(ei, deg);
  scan_kernel<<<1, 1024, 0, stream>>>(deg, rowstart);
  cursor_copy_kernel<<<(NN + 255) / 256, 256, 0, stream>>>(rowstart, cursor);
  fill_kernel<<<(NE + 255) / 256, 256, 0, stream>>>(ei, ea, cursor, src_sorted, ea_sorted);

  // graph segment bounds (batch is sorted)
  seg_bounds_kernel<<<1, GG + 1, 0, stream>>>(batch, bounds);

  dim3 mmg((NN + 127) / 128, 2);   // 391 x 2 blocks

  // ---- GAT layer 1 (K=64) ----
  matmul_mfma_kernel<64, true><<<mmg, 256, 0, stream>>>(h0, wt1l_hi, wt1l_lo, g1_bl, xl, NN);
  matmul_mfma_kernel<64, false><<<mmg, 256, 0, stream>>>(h0, wt1r_hi, wt1r_lo, nullptr, xr, NN);
  gat_fused_kernel<true><<<NN / 4, 256, 0, stream>>>(rowstart, src_sorted, ea_sorted,
                                                     xl, xr, g1_we, g1_att, g1_b,
                                                     nullptr, hb16);

  // ---- GAT layer 2 (K=256) ----
  matmul_mfma_kernel<256, true><<<mmg, 256, 0, stream>>>(hb16, wt2l_hi, wt2l_lo, g2_bl, xl, NN);
  matmul_mfma_kernel<256, false><<<mmg, 256, 0, stream>>>(hb16, wt2r_hi, wt2r_lo, nullptr, xr, NN);
  gat_fused_kernel<false><<<NN / 4, 256, 0, stream>>>(rowstart, src_sorted, ea_sorted,
                                                      xl, xr, g2_we, g2_att, g2_b,
                                                      hbuf, nullptr);

  // ---- pooling + MLP head ----
  pool_kernel<<<(NN + 255) / 256, 256, 0, stream>>>(hbuf, batch, pool);
  mlp_kernel<<<GG, 128, 0, stream>>>(pool, bounds, p1_w, p1_b, ln_g, ln_b,
                                     p2_w, p2_b, head_w, head_b, out);
}

// Round 12
// 499.992 us; speedup vs baseline: 3.1601x; 1.1267x over previous
//
#include <hip/hip_runtime.h>
#include <hip/hip_bf16.h>
#include <math.h>

#define NN 50000     // nodes
#define NE 400000    // edges
#define HH 4         // heads
#define CC 64        // per-head dim
#define HC 256       // H*C
#define GG 64        // graphs
#define NB 196       // scan blocks: ceil(NN/256)

typedef short v8s __attribute__((ext_vector_type(8)));
typedef float f32x4 __attribute__((ext_vector_type(4)));

static __device__ inline unsigned short f2bf(float v) {
  __hip_bfloat16 b = __float2bfloat16(v);
  return *reinterpret_cast<unsigned short*>(&b);
}
static __device__ inline float bf2f(unsigned short u) {
  __hip_bfloat16 b = *reinterpret_cast<__hip_bfloat16*>(&u);
  return __bfloat162float(b);
}
static __device__ inline void bf16split(float v, unsigned short& h, unsigned short& l) {
  h = f2bf(v);
  l = f2bf(v - bf2f(h));
}

// ---------------- encoder: h0 = relu(x @ enc_w + enc_b) -> bf16 ----------------
__global__ __launch_bounds__(256) void encoder_kernel(
    const float* __restrict__ x, const float* __restrict__ w,
    const float* __restrict__ b, unsigned short* __restrict__ h0) {
  int idx = blockIdx.x * 256 + threadIdx.x;   // N*64 threads
  int node = idx >> 6, col = idx & 63;
  const float* xr = x + node * 8;
  float acc = b[col];
#pragma unroll
  for (int k = 0; k < 8; ++k) acc += xr[k] * w[k * 64 + col];
  h0[idx] = f2bf(fmaxf(acc, 0.f));
}

// ---- W prep: W[K,256] f32 -> Wt hi/lo bf16 [256][K] (k-contiguous rows) ----
__global__ __launch_bounds__(256) void wconv_kernel(
    const float* __restrict__ W, int K,
    unsigned short* __restrict__ Wthi, unsigned short* __restrict__ Wtlo) {
  int idx = blockIdx.x * 256 + threadIdx.x;
  if (idx >= K * 256) return;
  int k = idx >> 8, n = idx & 255;
  unsigned short h, l;
  bf16split(W[idx], h, l);
  Wthi[n * K + k] = h;
  Wtlo[n * K + k] = l;
}

// ---------------- MFMA matmul: out[M,256] = A(bf16) @ (Whi+Wlo) (+bias) ----------------
// Block 128 rows x 128 cols, 4 waves (2x2), each wave 64x64 = 4x4 tiles of
// 16x16x32. LDS-staged A/Bhi/Blo chunks; split-W 2-MFMA into f32 acc.
template <int K, bool HAS_BIAS>
__global__ __launch_bounds__(256) void matmul_mfma_kernel(
    const unsigned short* __restrict__ A,
    const unsigned short* __restrict__ Wthi, const unsigned short* __restrict__ Wtlo,
    const float* __restrict__ bias, float* __restrict__ out, int M) {
  constexpr int AP = 40;                 // LDS k-stride (shorts): 80B, 16B-aligned
  __shared__ unsigned short a_lds[128 * AP];
  __shared__ unsigned short bh_lds[128 * AP];
  __shared__ unsigned short bl_lds[128 * AP];
  const int tid = threadIdx.x;
  const int wave = tid >> 6;
  const int lane = tid & 63;
  const int quad = lane >> 4;
  const int lrow = lane & 15;
  const int wr = (wave & 1) * 64;
  const int wc = (wave >> 1) * 64;
  const int r0 = blockIdx.x * 128;
  const int n0 = blockIdx.y * 128;

  f32x4 acc[4][4];
#pragma unroll
  for (int i = 0; i < 4; ++i)
#pragma unroll
    for (int j = 0; j < 4; ++j) acc[i][j] = (f32x4){0.f, 0.f, 0.f, 0.f};

  const int srow = tid >> 1;
  const int shalf = tid & 1;
  int agrow = r0 + srow; if (agrow >= M) agrow = M - 1;   // clamp; stores guarded
  const int bgrow = n0 + srow;

  for (int k0 = 0; k0 < K; k0 += 32) {
    {
      const float4* sa = (const float4*)&A[(size_t)agrow * K + k0 + shalf * 16];
      const float4* sh = (const float4*)&Wthi[(size_t)bgrow * K + k0 + shalf * 16];
      const float4* sl = (const float4*)&Wtlo[(size_t)bgrow * K + k0 + shalf * 16];
      float4 va0 = sa[0], va1 = sa[1];
      float4 vh0 = sh[0], vh1 = sh[1];
      float4 vl0 = sl[0], vl1 = sl[1];
      *(float4*)&a_lds[srow * AP + shalf * 16]      = va0;
      *(float4*)&a_lds[srow * AP + shalf * 16 + 8]  = va1;
      *(float4*)&bh_lds[srow * AP + shalf * 16]     = vh0;
      *(float4*)&bh_lds[srow * AP + shalf * 16 + 8] = vh1;
      *(float4*)&bl_lds[srow * AP + shalf * 16]     = vl0;
      *(float4*)&bl_lds[srow * AP + shalf * 16 + 8] = vl1;
    }
    __syncthreads();

    v8s af[4], bh[4], bl[4];
#pragma unroll
    for (int rt = 0; rt < 4; ++rt)
      af[rt] = *(const v8s*)&a_lds[(wr + rt * 16 + lrow) * AP + quad * 8];
#pragma unroll
    for (int ct = 0; ct < 4; ++ct) {
      bh[ct] = *(const v8s*)&bh_lds[(wc + ct * 16 + lrow) * AP + quad * 8];
      bl[ct] = *(const v8s*)&bl_lds[(wc + ct * 16 + lrow) * AP + quad * 8];
    }
#pragma unroll
    for (int rt = 0; rt < 4; ++rt)
#pragma unroll
      for (int ct = 0; ct < 4; ++ct) {
        acc[rt][ct] = __builtin_amdgcn_mfma_f32_16x16x32_bf16(af[rt], bl[ct], acc[rt][ct], 0, 0, 0);
        acc[rt][ct] = __builtin_amdgcn_mfma_f32_16x16x32_bf16(af[rt], bh[ct], acc[rt][ct], 0, 0, 0);
      }
    __syncthreads();
  }

#pragma unroll
  for (int rt = 0; rt < 4; ++rt) {
    int mbase = r0 + wr + rt * 16 + quad * 4;
#pragma unroll
    for (int ct = 0; ct < 4; ++ct) {
      int col = n0 + wc + ct * 16 + lrow;
      float b = HAS_BIAS ? bias[col] : 0.f;
#pragma unroll
      for (int r = 0; r < 4; ++r) {
        int row = mbase + r;
        if (row < M) out[(size_t)row * 256 + col] = acc[rt][ct][r] + b;
      }
    }
  }
}

// ---------------- CSR build ----------------
__global__ void degree_kernel(const int* __restrict__ ei, int* __restrict__ deg) {
  int e = blockIdx.x * 256 + threadIdx.x;
  if (e < NE) atomicAdd(&deg[ei[NE + e]], 1);
}

// hierarchical scan phase 1: coalesced per-block sums
__global__ __launch_bounds__(256) void blocksum_kernel(
    const int* __restrict__ deg, int* __restrict__ bsum) {
  int t = threadIdx.x;
  int i = blockIdx.x * 256 + t;
  int v = (i < NN) ? deg[i] : 0;
#pragma unroll
  for (int off = 32; off; off >>= 1) v += __shfl_down(v, off, 64);
  __shared__ int ws[4];
  if ((t & 63) == 0) ws[t >> 6] = v;
  __syncthreads();
  if (t == 0) bsum[blockIdx.x] = ws[0] + ws[1] + ws[2] + ws[3];
}

// phase 2: scan the 196 block sums (one small block)
__global__ __launch_bounds__(256) void blockscan_kernel(
    const int* __restrict__ bsum, int* __restrict__ bpre, int* __restrict__ rowstart) {
  __shared__ int s[256];
  int t = threadIdx.x;
  int v = (t < NB) ? bsum[t] : 0;
  s[t] = v;
  __syncthreads();
  for (int off = 1; off < 256; off <<= 1) {
    int x = s[t];
    int y = (t >= off) ? s[t - off] : 0;
    __syncthreads();
    s[t] = x + y;
    __syncthreads();
  }
  if (t < NB) bpre[t] = s[t] - v;        // exclusive block prefix
  if (t == 255) rowstart[NN] = s[255];   // total = NE
}

// phase 3: per-chunk scan + block prefix -> rowstart AND cursor (coalesced)
__global__ __launch_bounds__(256) void rowstart_kernel(
    const int* __restrict__ deg, const int* __restrict__ bpre,
    int* __restrict__ rowstart, int* __restrict__ cursor) {
  __shared__ int s[256];
  int t = threadIdx.x;
  int i = blockIdx.x * 256 + t;
  int v = (i < NN) ? deg[i] : 0;
  s[t] = v;
  __syncthreads();
  for (int off = 1; off < 256; off <<= 1) {
    int x = s[t];
    int y = (t >= off) ? s[t - off] : 0;
    __syncthreads();
    s[t] = x + y;
    __syncthreads();
  }
  if (i < NN) {
    int rs = bpre[blockIdx.x] + s[t] - v;  // exclusive
    rowstart[i] = rs;
    cursor[i] = rs;
  }
}

__global__ void fill_kernel(const int* __restrict__ ei, const float* __restrict__ ea,
                            int* __restrict__ cursor,
                            int* __restrict__ src_sorted, float* __restrict__ ea_sorted) {
  int e = blockIdx.x * 256 + threadIdx.x;
  if (e < NE) {
    int d = ei[NE + e];
    int pos = atomicAdd(&cursor[d], 1);
    src_sorted[pos] = ei[e];
    ea_sorted[pos] = ea[e];
  }
}

// ---------------- fused GATv2 edge phase: wave per dst node ----------------
template <bool OUTBF>
__global__ __launch_bounds__(256) void gat_fused_kernel(
    const int* __restrict__ rowstart, const int* __restrict__ src_sorted,
    const float* __restrict__ ea_sorted,
    const float* __restrict__ xl, const float* __restrict__ xr,
    const float* __restrict__ we, const float* __restrict__ att,
    const float* __restrict__ bias, float* __restrict__ outf,
    unsigned short* __restrict__ outb) {
  int node = (blockIdx.x * 256 + threadIdx.x) >> 6;
  int lane = threadIdx.x & 63;
  int r0 = rowstart[node], r1 = rowstart[node + 1];
  const float4* xl4 = (const float4*)xl;
  float4 r = ((const float4*)xr)[node * 64 + lane];
  float4 wv = ((const float4*)we)[lane];
  float4 at = ((const float4*)att)[lane];
  float4 acc = make_float4(0.f, 0.f, 0.f, 0.f);
  float denom = 0.f;

  auto edge_step = [&](float eav, float4 a) {
    float s0 = a.x + r.x + eav * wv.x;
    float s1 = a.y + r.y + eav * wv.y;
    float s2 = a.z + r.z + eav * wv.z;
    float s3 = a.w + r.w + eav * wv.w;
    s0 = s0 > 0.f ? s0 : 0.2f * s0;
    s1 = s1 > 0.f ? s1 : 0.2f * s1;
    s2 = s2 > 0.f ? s2 : 0.2f * s2;
    s3 = s3 > 0.f ? s3 : 0.2f * s3;
    float p = s0 * at.x + s1 * at.y + s2 * at.z + s3 * at.w;
#pragma unroll
    for (int off = 8; off; off >>= 1) p += __shfl_xor(p, off, 16);
    float ex = __expf(p);
    denom += ex;
    acc.x += ex * a.x; acc.y += ex * a.y; acc.z += ex * a.z; acc.w += ex * a.w;
  };

  int i = r0;
  for (; i + 2 <= r1; i += 2) {           // pairwise: 2 gathers in flight
    int s0i = src_sorted[i];
    int s1i = src_sorted[i + 1];
    float e0 = ea_sorted[i];
    float e1 = ea_sorted[i + 1];
    float4 a0 = xl4[(size_t)s0i * 64 + lane];
    float4 a1 = xl4[(size_t)s1i * 64 + lane];
    edge_step(e0, a0);
    edge_step(e1, a1);
  }
  if (i < r1) {
    int s0i = src_sorted[i];
    float e0 = ea_sorted[i];
    float4 a0 = xl4[(size_t)s0i * 64 + lane];
    edge_step(e0, a0);
  }

  float inv = 1.f / (denom + 1e-16f);
  float4 bv = ((const float4*)bias)[lane];
  float4 o;
  o.x = fmaxf(acc.x * inv + bv.x, 0.f);
  o.y = fmaxf(acc.y * inv + bv.y, 0.f);
  o.z = fmaxf(acc.z * inv + bv.z, 0.f);
  o.w = fmaxf(acc.w * inv + bv.w, 0.f);
  if (OUTBF) {
    uint2 pk;
    pk.x = (unsigned)f2bf(o.x) | ((unsigned)f2bf(o.y) << 16);
    pk.y = (unsigned)f2bf(o.z) | ((unsigned)f2bf(o.w) << 16);
    ((uint2*)outb)[(size_t)node * 64 + lane] = pk;
  } else {
    ((float4*)outf)[(size_t)node * 64 + lane] = o;
  }
}

// ---------------- segment bounds via binary search (batch is sorted) ----------------
__global__ void seg_bounds_kernel(const int* __restrict__ batch, int* __restrict__ bounds) {
  int g = threadIdx.x;                 // 0..GG inclusive
  if (g > GG) return;
  int lo = 0, hi = NN;
  while (lo < hi) {
    int mid = (lo + hi) >> 1;
    if (batch[mid] < g) lo = mid + 1; else hi = mid;
  }
  bounds[g] = lo;
}

__global__ __launch_bounds__(256) void pool_kernel(
    const float* __restrict__ h, const int* __restrict__ batch,
    float* __restrict__ pool) {
  int start = blockIdx.x * 256;
  int end = start + 256; if (end > NN) end = NN;
  int tid = threadIdx.x;
  int cur = batch[start];
  float acc = 0.f;
  for (int n = start; n < end; ++n) {
    int b = batch[n];
    if (b != cur) {
      atomicAdd(&pool[cur * 256 + tid], acc);
      acc = 0.f; cur = b;
    }
    acc += h[n * 256 + tid];
  }
  atomicAdd(&pool[cur * 256 + tid], acc);
}

// ---------------- final MLP: one block (128 thr) per graph ----------------
__global__ __launch_bounds__(128) void mlp_kernel(
    const float* __restrict__ pool, const int* __restrict__ bounds,
    const float* __restrict__ p1w, const float* __restrict__ p1b,
    const float* __restrict__ lng, const float* __restrict__ lnb,
    const float* __restrict__ p2w, const float* __restrict__ p2b,
    const float* __restrict__ hw, const float* __restrict__ hb,
    float* __restrict__ out) {
  __shared__ float sg[256];
  __shared__ float red[128];
  __shared__ float sz[128];
  __shared__ float s2[64];
  int b = blockIdx.x, tid = threadIdx.x;
  float cntf = (float)(bounds[b + 1] - bounds[b]);
  float invc = 1.f / fmaxf(cntf, 1.f);
  for (int i = tid; i < 256; i += 128) sg[i] = pool[b * 256 + i] * invc;
  __syncthreads();
  float z = p1b[tid];
  for (int k = 0; k < 256; ++k) z += sg[k] * p1w[k * 128 + tid];
  red[tid] = z; __syncthreads();
  for (int off = 64; off; off >>= 1) { if (tid < off) red[tid] += red[tid + off]; __syncthreads(); }
  float mu = red[0] * (1.f / 128.f);
  __syncthreads();
  float d = z - mu;
  red[tid] = d * d; __syncthreads();
  for (int off = 64; off; off >>= 1) { if (tid < off) red[tid] += red[tid + off]; __syncthreads(); }
  float var = red[0] * (1.f / 128.f);
  float zn = d * rsqrtf(var + 1e-5f) * lng[tid] + lnb[tid];
  sz[tid] = fmaxf(zn, 0.f);
  __syncthreads();
  if (tid < 64) {
    float a = p2b[tid];
    for (int k = 0; k < 128; ++k) a += sz[k] * p2w[k * 64 + tid];
    s2[tid] = fmaxf(a, 0.f);
  }
  __syncthreads();
  if (tid < 64) {
    float p = s2[tid] * hw[tid];
    for (int off = 32; off; off >>= 1) p += __shfl_down(p, off, 64);
    if (tid == 0) out[b] = p + hb[0];
  }
}

extern "C" void kernel_launch(void* const* d_in, const int* in_sizes, int n_in,
                              void* d_out, int out_size, void* d_ws, size_t ws_size,
                              hipStream_t stream) {
  const float* x      = (const float*)d_in[0];
  const int*   ei     = (const int*)d_in[1];
  const float* ea     = (const float*)d_in[2];
  const int*   batch  = (const int*)d_in[3];
  const float* enc_w  = (const float*)d_in[4];
  const float* enc_b  = (const float*)d_in[5];
  const float* g1_wl  = (const float*)d_in[6];
  const float* g1_bl  = (const float*)d_in[7];
  const float* g1_wr  = (const float*)d_in[8];
  const float* g1_we  = (const float*)d_in[9];
  const float* g1_att = (const float*)d_in[10];
  const float* g1_b   = (const float*)d_in[11];
  const float* g2_wl  = (const float*)d_in[12];
  const float* g2_bl  = (const float*)d_in[13];
  const float* g2_wr  = (const float*)d_in[14];
  const float* g2_we  = (const float*)d_in[15];
  const float* g2_att = (const float*)d_in[16];
  const float* g2_b   = (const float*)d_in[17];
  const float* p1_w   = (const float*)d_in[18];
  const float* p1_b   = (const float*)d_in[19];
  const float* ln_g   = (const float*)d_in[20];
  const float* ln_b   = (const float*)d_in[21];
  const float* p2_w   = (const float*)d_in[22];
  const float* p2_b   = (const float*)d_in[23];
  const float* head_w = (const float*)d_in[24];
  const float* head_b = (const float*)d_in[25];
  float* out = (float*)d_out;

  char* ws = (char*)d_ws;
  size_t off = 0;
  auto alloc = [&](size_t bytes) -> void* {
    void* p = ws + off;
    off = (off + bytes + 255) & ~(size_t)255;
    return p;
  };
  float* xl        = (float*)alloc((size_t)NN * HC * 4);
  float* xr        = (float*)alloc((size_t)NN * HC * 4);
  float* hbuf      = (float*)alloc((size_t)NN * HC * 4);
  unsigned short* h0   = (unsigned short*)alloc((size_t)NN * 64 * 2);
  unsigned short* hb16 = (unsigned short*)alloc((size_t)NN * HC * 2);
  unsigned short* wt1l_hi = (unsigned short*)alloc((size_t)64 * 256 * 2);
  unsigned short* wt1l_lo = (unsigned short*)alloc((size_t)64 * 256 * 2);
  unsigned short* wt1r_hi = (unsigned short*)alloc((size_t)64 * 256 * 2);
  unsigned short* wt1r_lo = (unsigned short*)alloc((size_t)64 * 256 * 2);
  unsigned short* wt2l_hi = (unsigned short*)alloc((size_t)256 * 256 * 2);
  unsigned short* wt2l_lo = (unsigned short*)alloc((size_t)256 * 256 * 2);
  unsigned short* wt2r_hi = (unsigned short*)alloc((size_t)256 * 256 * 2);
  unsigned short* wt2r_lo = (unsigned short*)alloc((size_t)256 * 256 * 2);
  float* pool      = (float*)alloc((size_t)GG * HC * 4);
  int*   deg       = (int*)alloc((size_t)NN * 4);
  int*   rowstart  = (int*)alloc((size_t)(NN + 1) * 4);
  int*   cursor    = (int*)alloc((size_t)NN * 4);
  int*   bsum      = (int*)alloc((size_t)NB * 4);
  int*   bpre      = (int*)alloc((size_t)NB * 4);
  int*   src_sorted= (int*)alloc((size_t)NE * 4);
  float* ea_sorted = (float*)alloc((size_t)NE * 4);
  int*   bounds    = (int*)alloc((size_t)(GG + 1) * 4);

  hipMemsetAsync(deg, 0, (size_t)NN * 4, stream);
  hipMemsetAsync(pool, 0, (size_t)GG * HC * 4, stream);

  // encoder (bf16 out) + weight prep
  encoder_kernel<<<NN * 64 / 256, 256, 0, stream>>>(x, enc_w, enc_b, h0);
  wconv_kernel<<<64, 256, 0, stream>>>(g1_wl, 64, wt1l_hi, wt1l_lo);
  wconv_kernel<<<64, 256, 0, stream>>>(g1_wr, 64, wt1r_hi, wt1r_lo);
  wconv_kernel<<<256, 256, 0, stream>>>(g2_wl, 256, wt2l_hi, wt2l_lo);
  wconv_kernel<<<256, 256, 0, stream>>>(g2_wr, 256, wt2r_hi, wt2r_lo);

  // CSR build: degree -> hierarchical scan -> fill (coalesced; replaces the
  // 77us single-block scan_kernel + cursor_copy)
  degree_kernel<<<(NE + 255) / 256, 256, 0, stream>>>(ei, deg);
  blocksum_kernel<<<NB, 256, 0, stream>>>(deg, bsum);
  blockscan_kernel<<<1, 256, 0, stream>>>(bsum, bpre, rowstart);
  rowstart_kernel<<<NB, 256, 0, stream>>>(deg, bpre, rowstart, cursor);
  fill_kernel<<<(NE + 255) / 256, 256, 0, stream>>>(ei, ea, cursor, src_sorted, ea_sorted);

  // graph segment bounds (batch is sorted)
  seg_bounds_kernel<<<1, GG + 1, 0, stream>>>(batch, bounds);

  dim3 mmg((NN + 127) / 128, 2);   // 391 x 2 blocks

  // ---- GAT layer 1 (K=64) ----
  matmul_mfma_kernel<64, true><<<mmg, 256, 0, stream>>>(h0, wt1l_hi, wt1l_lo, g1_bl, xl, NN);
  matmul_mfma_kernel<64, false><<<mmg, 256, 0, stream>>>(h0, wt1r_hi, wt1r_lo, nullptr, xr, NN);
  gat_fused_kernel<true><<<NN / 4, 256, 0, stream>>>(rowstart, src_sorted, ea_sorted,
                                                     xl, xr, g1_we, g1_att, g1_b,
                                                     nullptr, hb16);

  // ---- GAT layer 2 (K=256) ----
  matmul_mfma_kernel<256, true><<<mmg, 256, 0, stream>>>(hb16, wt2l_hi, wt2l_lo, g2_bl, xl, NN);
  matmul_mfma_kernel<256, false><<<mmg, 256, 0, stream>>>(hb16, wt2r_hi, wt2r_lo, nullptr, xr, NN);
  gat_fused_kernel<false><<<NN / 4, 256, 0, stream>>>(rowstart, src_sorted, ea_sorted,
                                                      xl, xr, g2_we, g2_att, g2_b,
                                                      hbuf, nullptr);

  // ---- pooling + MLP head ----
  pool_kernel<<<(NN + 255) / 256, 256, 0, stream>>>(hbuf, batch, pool);
  mlp_kernel<<<GG, 128, 0, stream>>>(pool, bounds, p1_w, p1_b, ln_g, ln_b,
                                     p2_w, p2_b, head_w, head_b, out);
}

// Round 13
// 450.774 us; speedup vs baseline: 3.5051x; 1.1092x over previous
//
#include <hip/hip_runtime.h>
#include <hip/hip_bf16.h>
#include <math.h>

#define NN 50000     // nodes
#define NE 400000    // edges
#define HH 4         // heads
#define CC 64        // per-head dim
#define HC 256       // H*C
#define GG 64        // graphs
#define NB 196       // scan blocks: ceil(NN/256)

typedef short v8s __attribute__((ext_vector_type(8)));
typedef float f32x4 __attribute__((ext_vector_type(4)));

static __device__ inline unsigned short f2bf(float v) {
  __hip_bfloat16 b = __float2bfloat16(v);
  return *reinterpret_cast<unsigned short*>(&b);
}
static __device__ inline float bf2f(unsigned short u) {
  __hip_bfloat16 b = *reinterpret_cast<__hip_bfloat16*>(&u);
  return __bfloat162float(b);
}
static __device__ inline void bf16split(float v, unsigned short& h, unsigned short& l) {
  h = f2bf(v);
  l = f2bf(v - bf2f(h));
}

// ---------------- encoder: h0 = relu(x @ enc_w + enc_b) -> bf16 ----------------
__global__ __launch_bounds__(256) void encoder_kernel(
    const float* __restrict__ x, const float* __restrict__ w,
    const float* __restrict__ b, unsigned short* __restrict__ h0) {
  int idx = blockIdx.x * 256 + threadIdx.x;   // N*64 threads
  int node = idx >> 6, col = idx & 63;
  const float* xr = x + node * 8;
  float acc = b[col];
#pragma unroll
  for (int k = 0; k < 8; ++k) acc += xr[k] * w[k * 64 + col];
  h0[idx] = f2bf(fmaxf(acc, 0.f));
}

// ---- W prep: W[K,256] f32 -> Wt hi/lo bf16 [256][K] (k-contiguous rows) ----
__global__ __launch_bounds__(256) void wconv_kernel(
    const float* __restrict__ W, int K,
    unsigned short* __restrict__ Wthi, unsigned short* __restrict__ Wtlo) {
  int idx = blockIdx.x * 256 + threadIdx.x;
  if (idx >= K * 256) return;
  int k = idx >> 8, n = idx & 255;
  unsigned short h, l;
  bf16split(W[idx], h, l);
  Wthi[n * K + k] = h;
  Wtlo[n * K + k] = l;
}

// ---------------- MFMA matmul: out[M,256] = A(bf16) @ (Whi+Wlo) (+bias) ----------------
template <int K, bool HAS_BIAS>
__global__ __launch_bounds__(256) void matmul_mfma_kernel(
    const unsigned short* __restrict__ A,
    const unsigned short* __restrict__ Wthi, const unsigned short* __restrict__ Wtlo,
    const float* __restrict__ bias, float* __restrict__ out, int M) {
  constexpr int AP = 40;                 // LDS k-stride (shorts): 80B, 16B-aligned
  __shared__ unsigned short a_lds[128 * AP];
  __shared__ unsigned short bh_lds[128 * AP];
  __shared__ unsigned short bl_lds[128 * AP];
  const int tid = threadIdx.x;
  const int wave = tid >> 6;
  const int lane = tid & 63;
  const int quad = lane >> 4;
  const int lrow = lane & 15;
  const int wr = (wave & 1) * 64;
  const int wc = (wave >> 1) * 64;
  const int r0 = blockIdx.x * 128;
  const int n0 = blockIdx.y * 128;

  f32x4 acc[4][4];
#pragma unroll
  for (int i = 0; i < 4; ++i)
#pragma unroll
    for (int j = 0; j < 4; ++j) acc[i][j] = (f32x4){0.f, 0.f, 0.f, 0.f};

  const int srow = tid >> 1;
  const int shalf = tid & 1;
  int agrow = r0 + srow; if (agrow >= M) agrow = M - 1;   // clamp; stores guarded
  const int bgrow = n0 + srow;

  for (int k0 = 0; k0 < K; k0 += 32) {
    {
      const float4* sa = (const float4*)&A[(size_t)agrow * K + k0 + shalf * 16];
      const float4* sh = (const float4*)&Wthi[(size_t)bgrow * K + k0 + shalf * 16];
      const float4* sl = (const float4*)&Wtlo[(size_t)bgrow * K + k0 + shalf * 16];
      float4 va0 = sa[0], va1 = sa[1];
      float4 vh0 = sh[0], vh1 = sh[1];
      float4 vl0 = sl[0], vl1 = sl[1];
      *(float4*)&a_lds[srow * AP + shalf * 16]      = va0;
      *(float4*)&a_lds[srow * AP + shalf * 16 + 8]  = va1;
      *(float4*)&bh_lds[srow * AP + shalf * 16]     = vh0;
      *(float4*)&bh_lds[srow * AP + shalf * 16 + 8] = vh1;
      *(float4*)&bl_lds[srow * AP + shalf * 16]     = vl0;
      *(float4*)&bl_lds[srow * AP + shalf * 16 + 8] = vl1;
    }
    __syncthreads();

    v8s af[4], bh[4], bl[4];
#pragma unroll
    for (int rt = 0; rt < 4; ++rt)
      af[rt] = *(const v8s*)&a_lds[(wr + rt * 16 + lrow) * AP + quad * 8];
#pragma unroll
    for (int ct = 0; ct < 4; ++ct) {
      bh[ct] = *(const v8s*)&bh_lds[(wc + ct * 16 + lrow) * AP + quad * 8];
      bl[ct] = *(const v8s*)&bl_lds[(wc + ct * 16 + lrow) * AP + quad * 8];
    }
#pragma unroll
    for (int rt = 0; rt < 4; ++rt)
#pragma unroll
      for (int ct = 0; ct < 4; ++ct) {
        acc[rt][ct] = __builtin_amdgcn_mfma_f32_16x16x32_bf16(af[rt], bl[ct], acc[rt][ct], 0, 0, 0);
        acc[rt][ct] = __builtin_amdgcn_mfma_f32_16x16x32_bf16(af[rt], bh[ct], acc[rt][ct], 0, 0, 0);
      }
    __syncthreads();
  }

#pragma unroll
  for (int rt = 0; rt < 4; ++rt) {
    int mbase = r0 + wr + rt * 16 + quad * 4;
#pragma unroll
    for (int ct = 0; ct < 4; ++ct) {
      int col = n0 + wc + ct * 16 + lrow;
      float b = HAS_BIAS ? bias[col] : 0.f;
#pragma unroll
      for (int r = 0; r < 4; ++r) {
        int row = mbase + r;
        if (row < M) out[(size_t)row * 256 + col] = acc[rt][ct][r] + b;
      }
    }
  }
}

// ---------------- CSR build ----------------
__global__ void degree_kernel(const int* __restrict__ ei, int* __restrict__ deg) {
  int e = blockIdx.x * 256 + threadIdx.x;
  if (e < NE) atomicAdd(&deg[ei[NE + e]], 1);
}

__global__ __launch_bounds__(256) void blocksum_kernel(
    const int* __restrict__ deg, int* __restrict__ bsum) {
  int t = threadIdx.x;
  int i = blockIdx.x * 256 + t;
  int v = (i < NN) ? deg[i] : 0;
#pragma unroll
  for (int off = 32; off; off >>= 1) v += __shfl_down(v, off, 64);
  __shared__ int ws[4];
  if ((t & 63) == 0) ws[t >> 6] = v;
  __syncthreads();
  if (t == 0) bsum[blockIdx.x] = ws[0] + ws[1] + ws[2] + ws[3];
}

__global__ __launch_bounds__(256) void blockscan_kernel(
    const int* __restrict__ bsum, int* __restrict__ bpre, int* __restrict__ rowstart) {
  __shared__ int s[256];
  int t = threadIdx.x;
  int v = (t < NB) ? bsum[t] : 0;
  s[t] = v;
  __syncthreads();
  for (int off = 1; off < 256; off <<= 1) {
    int x = s[t];
    int y = (t >= off) ? s[t - off] : 0;
    __syncthreads();
    s[t] = x + y;
    __syncthreads();
  }
  if (t < NB) bpre[t] = s[t] - v;
  if (t == 255) rowstart[NN] = s[255];
}

__global__ __launch_bounds__(256) void rowstart_kernel(
    const int* __restrict__ deg, const int* __restrict__ bpre,
    int* __restrict__ rowstart, int* __restrict__ cursor) {
  __shared__ int s[256];
  int t = threadIdx.x;
  int i = blockIdx.x * 256 + t;
  int v = (i < NN) ? deg[i] : 0;
  s[t] = v;
  __syncthreads();
  for (int off = 1; off < 256; off <<= 1) {
    int x = s[t];
    int y = (t >= off) ? s[t - off] : 0;
    __syncthreads();
    s[t] = x + y;
    __syncthreads();
  }
  if (i < NN) {
    int rs = bpre[blockIdx.x] + s[t] - v;
    rowstart[i] = rs;
    cursor[i] = rs;
  }
}

__global__ void fill_kernel(const int* __restrict__ ei, const float* __restrict__ ea,
                            int* __restrict__ cursor,
                            int* __restrict__ src_sorted, float* __restrict__ ea_sorted) {
  int e = blockIdx.x * 256 + threadIdx.x;
  if (e < NE) {
    int d = ei[NE + e];
    int pos = atomicAdd(&cursor[d], 1);
    src_sorted[pos] = ei[e];
    ea_sorted[pos] = ea[e];
  }
}

// ---------------- fused GATv2 edge phase: wave per dst node ----------------
template <bool OUTBF>
__global__ __launch_bounds__(256) void gat_fused_kernel(
    const int* __restrict__ rowstart, const int* __restrict__ src_sorted,
    const float* __restrict__ ea_sorted,
    const float* __restrict__ xl, const float* __restrict__ xr,
    const float* __restrict__ we, const float* __restrict__ att,
    const float* __restrict__ bias, float* __restrict__ outf,
    unsigned short* __restrict__ outb) {
  int node = (blockIdx.x * 256 + threadIdx.x) >> 6;
  int lane = threadIdx.x & 63;
  int r0 = rowstart[node], r1 = rowstart[node + 1];
  const float4* xl4 = (const float4*)xl;
  float4 r = ((const float4*)xr)[node * 64 + lane];
  float4 wv = ((const float4*)we)[lane];
  float4 at = ((const float4*)att)[lane];
  float4 acc = make_float4(0.f, 0.f, 0.f, 0.f);
  float denom = 0.f;

  auto edge_step = [&](float eav, float4 a) {
    float s0 = a.x + r.x + eav * wv.x;
    float s1 = a.y + r.y + eav * wv.y;
    float s2 = a.z + r.z + eav * wv.z;
    float s3 = a.w + r.w + eav * wv.w;
    s0 = s0 > 0.f ? s0 : 0.2f * s0;
    s1 = s1 > 0.f ? s1 : 0.2f * s1;
    s2 = s2 > 0.f ? s2 : 0.2f * s2;
    s3 = s3 > 0.f ? s3 : 0.2f * s3;
    float p = s0 * at.x + s1 * at.y + s2 * at.z + s3 * at.w;
#pragma unroll
    for (int off = 8; off; off >>= 1) p += __shfl_xor(p, off, 16);
    float ex = __expf(p);
    denom += ex;
    acc.x += ex * a.x; acc.y += ex * a.y; acc.z += ex * a.z; acc.w += ex * a.w;
  };

  int i = r0;
  for (; i + 2 <= r1; i += 2) {           // pairwise: 2 gathers in flight
    int s0i = src_sorted[i];
    int s1i = src_sorted[i + 1];
    float e0 = ea_sorted[i];
    float e1 = ea_sorted[i + 1];
    float4 a0 = xl4[(size_t)s0i * 64 + lane];
    float4 a1 = xl4[(size_t)s1i * 64 + lane];
    edge_step(e0, a0);
    edge_step(e1, a1);
  }
  if (i < r1) {
    int s0i = src_sorted[i];
    float e0 = ea_sorted[i];
    float4 a0 = xl4[(size_t)s0i * 64 + lane];
    edge_step(e0, a0);
  }

  float inv = 1.f / (denom + 1e-16f);
  float4 bv = ((const float4*)bias)[lane];
  float4 o;
  o.x = fmaxf(acc.x * inv + bv.x, 0.f);
  o.y = fmaxf(acc.y * inv + bv.y, 0.f);
  o.z = fmaxf(acc.z * inv + bv.z, 0.f);
  o.w = fmaxf(acc.w * inv + bv.w, 0.f);
  if (OUTBF) {
    uint2 pk;
    pk.x = (unsigned)f2bf(o.x) | ((unsigned)f2bf(o.y) << 16);
    pk.y = (unsigned)f2bf(o.z) | ((unsigned)f2bf(o.w) << 16);
    ((uint2*)outb)[(size_t)node * 64 + lane] = pk;
  } else {
    ((float4*)outf)[(size_t)node * 64 + lane] = o;
  }
}

// ---------------- segment bounds via binary search (batch is sorted) ----------------
__global__ void seg_bounds_kernel(const int* __restrict__ batch, int* __restrict__ bounds) {
  int g = threadIdx.x;                 // 0..GG inclusive
  if (g > GG) return;
  int lo = 0, hi = NN;
  while (lo < hi) {
    int mid = (lo + hi) >> 1;
    if (batch[mid] < g) lo = mid + 1; else hi = mid;
  }
  bounds[g] = lo;
}

// ---------------- pooling: block = 64 nodes, 4 row-groups x 64 lanes (float4) ----
// 782 blocks / 3128 concurrent row-streams (was 196 / 196: 7.8% occupancy,
// latency-bound at 0.35 TB/s). batch[n] is wave-uniform -> scalar load.
// Run-length accumulate per row-group, atomicAdd flush on graph transition.
__global__ __launch_bounds__(256) void pool_kernel(
    const float* __restrict__ h, const int* __restrict__ batch,
    float* __restrict__ pool) {
  int rg = threadIdx.x >> 6;
  int lane = threadIdx.x & 63;
  int n0 = blockIdx.x * 64;
  const float4* h4 = (const float4*)h;
  float4 acc = make_float4(0.f, 0.f, 0.f, 0.f);
  int cur = -1;
#pragma unroll 4
  for (int i = 0; i < 16; ++i) {
    int n = n0 + rg + 4 * i;
    if (n >= NN) break;
    int b = batch[n];
    if (b != cur) {
      if (cur >= 0) {
        float* p = &pool[cur * 256 + lane * 4];
        atomicAdd(p + 0, acc.x); atomicAdd(p + 1, acc.y);
        atomicAdd(p + 2, acc.z); atomicAdd(p + 3, acc.w);
      }
      cur = b;
      acc = make_float4(0.f, 0.f, 0.f, 0.f);
    }
    float4 v = h4[(size_t)n * 64 + lane];
    acc.x += v.x; acc.y += v.y; acc.z += v.z; acc.w += v.w;
  }
  if (cur >= 0) {
    float* p = &pool[cur * 256 + lane * 4];
    atomicAdd(p + 0, acc.x); atomicAdd(p + 1, acc.y);
    atomicAdd(p + 2, acc.z); atomicAdd(p + 3, acc.w);
  }
}

// ---------------- final MLP: one block (128 thr) per graph ----------------
__global__ __launch_bounds__(128) void mlp_kernel(
    const float* __restrict__ pool, const int* __restrict__ bounds,
    const float* __restrict__ p1w, const float* __restrict__ p1b,
    const float* __restrict__ lng, const float* __restrict__ lnb,
    const float* __restrict__ p2w, const float* __restrict__ p2b,
    const float* __restrict__ hw, const float* __restrict__ hb,
    float* __restrict__ out) {
  __shared__ float sg[256];
  __shared__ float red[128];
  __shared__ float sz[128];
  __shared__ float s2[64];
  int b = blockIdx.x, tid = threadIdx.x;
  float cntf = (float)(bounds[b + 1] - bounds[b]);
  float invc = 1.f / fmaxf(cntf, 1.f);
  for (int i = tid; i < 256; i += 128) sg[i] = pool[b * 256 + i] * invc;
  __syncthreads();
  float z = p1b[tid];
  for (int k = 0; k < 256; ++k) z += sg[k] * p1w[k * 128 + tid];
  red[tid] = z; __syncthreads();
  for (int off = 64; off; off >>= 1) { if (tid < off) red[tid] += red[tid + off]; __syncthreads(); }
  float mu = red[0] * (1.f / 128.f);
  __syncthreads();
  float d = z - mu;
  red[tid] = d * d; __syncthreads();
  for (int off = 64; off; off >>= 1) { if (tid < off) red[tid] += red[tid + off]; __syncthreads(); }
  float var = red[0] * (1.f / 128.f);
  float zn = d * rsqrtf(var + 1e-5f) * lng[tid] + lnb[tid];
  sz[tid] = fmaxf(zn, 0.f);
  __syncthreads();
  if (tid < 64) {
    float a = p2b[tid];
    for (int k = 0; k < 128; ++k) a += sz[k] * p2w[k * 64 + tid];
    s2[tid] = fmaxf(a, 0.f);
  }
  __syncthreads();
  if (tid < 64) {
    float p = s2[tid] * hw[tid];
    for (int off = 32; off; off >>= 1) p += __shfl_down(p, off, 64);
    if (tid == 0) out[b] = p + hb[0];
  }
}

extern "C" void kernel_launch(void* const* d_in, const int* in_sizes, int n_in,
                              void* d_out, int out_size, void* d_ws, size_t ws_size,
                              hipStream_t stream) {
  const float* x      = (const float*)d_in[0];
  const int*   ei     = (const int*)d_in[1];
  const float* ea     = (const float*)d_in[2];
  const int*   batch  = (const int*)d_in[3];
  const float* enc_w  = (const float*)d_in[4];
  const float* enc_b  = (const float*)d_in[5];
  const float* g1_wl  = (const float*)d_in[6];
  const float* g1_bl  = (const float*)d_in[7];
  const float* g1_wr  = (const float*)d_in[8];
  const float* g1_we  = (const float*)d_in[9];
  const float* g1_att = (const float*)d_in[10];
  const float* g1_b   = (const float*)d_in[11];
  const float* g2_wl  = (const float*)d_in[12];
  const float* g2_bl  = (const float*)d_in[13];
  const float* g2_wr  = (const float*)d_in[14];
  const float* g2_we  = (const float*)d_in[15];
  const float* g2_att = (const float*)d_in[16];
  const float* g2_b   = (const float*)d_in[17];
  const float* p1_w   = (const float*)d_in[18];
  const float* p1_b   = (const float*)d_in[19];
  const float* ln_g   = (const float*)d_in[20];
  const float* ln_b   = (const float*)d_in[21];
  const float* p2_w   = (const float*)d_in[22];
  const float* p2_b   = (const float*)d_in[23];
  const float* head_w = (const float*)d_in[24];
  const float* head_b = (const float*)d_in[25];
  float* out = (float*)d_out;

  char* ws = (char*)d_ws;
  size_t off = 0;
  auto alloc = [&](size_t bytes) -> void* {
    void* p = ws + off;
    off = (off + bytes + 255) & ~(size_t)255;
    return p;
  };
  float* xl        = (float*)alloc((size_t)NN * HC * 4);
  float* xr        = (float*)alloc((size_t)NN * HC * 4);
  float* hbuf      = (float*)alloc((size_t)NN * HC * 4);
  unsigned short* h0   = (unsigned short*)alloc((size_t)NN * 64 * 2);
  unsigned short* hb16 = (unsigned short*)alloc((size_t)NN * HC * 2);
  unsigned short* wt1l_hi = (unsigned short*)alloc((size_t)64 * 256 * 2);
  unsigned short* wt1l_lo = (unsigned short*)alloc((size_t)64 * 256 * 2);
  unsigned short* wt1r_hi = (unsigned short*)alloc((size_t)64 * 256 * 2);
  unsigned short* wt1r_lo = (unsigned short*)alloc((size_t)64 * 256 * 2);
  unsigned short* wt2l_hi = (unsigned short*)alloc((size_t)256 * 256 * 2);
  unsigned short* wt2l_lo = (unsigned short*)alloc((size_t)256 * 256 * 2);
  unsigned short* wt2r_hi = (unsigned short*)alloc((size_t)256 * 256 * 2);
  unsigned short* wt2r_lo = (unsigned short*)alloc((size_t)256 * 256 * 2);
  float* pool      = (float*)alloc((size_t)GG * HC * 4);
  int*   deg       = (int*)alloc((size_t)NN * 4);
  int*   rowstart  = (int*)alloc((size_t)(NN + 1) * 4);
  int*   cursor    = (int*)alloc((size_t)NN * 4);
  int*   bsum      = (int*)alloc((size_t)NB * 4);
  int*   bpre      = (int*)alloc((size_t)NB * 4);
  int*   src_sorted= (int*)alloc((size_t)NE * 4);
  float* ea_sorted = (float*)alloc((size_t)NE * 4);
  int*   bounds    = (int*)alloc((size_t)(GG + 1) * 4);

  hipMemsetAsync(deg, 0, (size_t)NN * 4, stream);
  hipMemsetAsync(pool, 0, (size_t)GG * HC * 4, stream);

  // encoder (bf16 out) + weight prep
  encoder_kernel<<<NN * 64 / 256, 256, 0, stream>>>(x, enc_w, enc_b, h0);
  wconv_kernel<<<64, 256, 0, stream>>>(g1_wl, 64, wt1l_hi, wt1l_lo);
  wconv_kernel<<<64, 256, 0, stream>>>(g1_wr, 64, wt1r_hi, wt1r_lo);
  wconv_kernel<<<256, 256, 0, stream>>>(g2_wl, 256, wt2l_hi, wt2l_lo);
  wconv_kernel<<<256, 256, 0, stream>>>(g2_wr, 256, wt2r_hi, wt2r_lo);

  // CSR build: degree -> hierarchical scan -> fill
  degree_kernel<<<(NE + 255) / 256, 256, 0, stream>>>(ei, deg);
  blocksum_kernel<<<NB, 256, 0, stream>>>(deg, bsum);
  blockscan_kernel<<<1, 256, 0, stream>>>(bsum, bpre, rowstart);
  rowstart_kernel<<<NB, 256, 0, stream>>>(deg, bpre, rowstart, cursor);
  fill_kernel<<<(NE + 255) / 256, 256, 0, stream>>>(ei, ea, cursor, src_sorted, ea_sorted);

  // graph segment bounds (batch is sorted)
  seg_bounds_kernel<<<1, GG + 1, 0, stream>>>(batch, bounds);

  dim3 mmg((NN + 127) / 128, 2);   // 391 x 2 blocks

  // ---- GAT layer 1 (K=64) ----
  matmul_mfma_kernel<64, true><<<mmg, 256, 0, stream>>>(h0, wt1l_hi, wt1l_lo, g1_bl, xl, NN);
  matmul_mfma_kernel<64, false><<<mmg, 256, 0, stream>>>(h0, wt1r_hi, wt1r_lo, nullptr, xr, NN);
  gat_fused_kernel<true><<<NN / 4, 256, 0, stream>>>(rowstart, src_sorted, ea_sorted,
                                                     xl, xr, g1_we, g1_att, g1_b,
                                                     nullptr, hb16);

  // ---- GAT layer 2 (K=256) ----
  matmul_mfma_kernel<256, true><<<mmg, 256, 0, stream>>>(hb16, wt2l_hi, wt2l_lo, g2_bl, xl, NN);
  matmul_mfma_kernel<256, false><<<mmg, 256, 0, stream>>>(hb16, wt2r_hi, wt2r_lo, nullptr, xr, NN);
  gat_fused_kernel<false><<<NN / 4, 256, 0, stream>>>(rowstart, src_sorted, ea_sorted,
                                                      xl, xr, g2_we, g2_att, g2_b,
                                                      hbuf, nullptr);

  // ---- pooling + MLP head ----
  pool_kernel<<<(NN + 63) / 64, 256, 0, stream>>>(hbuf, batch, pool);
  mlp_kernel<<<GG, 128, 0, stream>>>(pool, bounds, p1_w, p1_b, ln_g, ln_b,
                                     p2_w, p2_b, head_w, head_b, out);
}

// Round 14
// 398.872 us; speedup vs baseline: 3.9612x; 1.1301x over previous
//
#include <hip/hip_runtime.h>
#include <hip/hip_bf16.h>
#include <math.h>

#define NN 50000     // nodes
#define NE 400000    // edges
#define HH 4         // heads
#define CC 64        // per-head dim
#define HC 256       // H*C
#define GG 64        // graphs
#define NB 196       // scan blocks: ceil(NN/256)

typedef short v8s __attribute__((ext_vector_type(8)));
typedef float f32x4 __attribute__((ext_vector_type(4)));

static __device__ inline unsigned short f2bf(float v) {
  __hip_bfloat16 b = __float2bfloat16(v);
  return *reinterpret_cast<unsigned short*>(&b);
}
static __device__ inline float bf2f(unsigned short u) {
  __hip_bfloat16 b = *reinterpret_cast<__hip_bfloat16*>(&u);
  return __bfloat162float(b);
}
static __device__ inline void bf16split(float v, unsigned short& h, unsigned short& l) {
  h = f2bf(v);
  l = f2bf(v - bf2f(h));
}
// packed bf16 pair -> f32 (bf16 value = bit pattern << 16)
static __device__ inline float bflo(unsigned u) { return __uint_as_float(u << 16); }
static __device__ inline float bfhi(unsigned u) { return __uint_as_float(u & 0xffff0000u); }

// ---------------- encoder: h0 = relu(x @ enc_w + enc_b) -> bf16 ----------------
__global__ __launch_bounds__(256) void encoder_kernel(
    const float* __restrict__ x, const float* __restrict__ w,
    const float* __restrict__ b, unsigned short* __restrict__ h0) {
  int idx = blockIdx.x * 256 + threadIdx.x;   // N*64 threads
  int node = idx >> 6, col = idx & 63;
  const float* xr = x + node * 8;
  float acc = b[col];
#pragma unroll
  for (int k = 0; k < 8; ++k) acc += xr[k] * w[k * 64 + col];
  h0[idx] = f2bf(fmaxf(acc, 0.f));
}

// ---- W prep: W[K,256] f32 -> Wt hi/lo bf16 [256][K] (k-contiguous rows) ----
__global__ __launch_bounds__(256) void wconv_kernel(
    const float* __restrict__ W, int K,
    unsigned short* __restrict__ Wthi, unsigned short* __restrict__ Wtlo) {
  int idx = blockIdx.x * 256 + threadIdx.x;
  if (idx >= K * 256) return;
  int k = idx >> 8, n = idx & 255;
  unsigned short h, l;
  bf16split(W[idx], h, l);
  Wthi[n * K + k] = h;
  Wtlo[n * K + k] = l;
}

// ---------------- MFMA matmul: out(bf16)[M,256] = A(bf16) @ (Whi+Wlo) (+bias) ----------
// Block 128x128, 4 waves (2x2), each wave 64x64 = 4x4 tiles of 16x16x32.
// LDS-staged A/Bhi/Blo; split-W 2-MFMA into f32 acc; epilogue rounds to bf16
// (the gather phase reads rows at half the bytes).
template <int K, bool HAS_BIAS>
__global__ __launch_bounds__(256) void matmul_mfma_kernel(
    const unsigned short* __restrict__ A,
    const unsigned short* __restrict__ Wthi, const unsigned short* __restrict__ Wtlo,
    const float* __restrict__ bias, unsigned short* __restrict__ out, int M) {
  constexpr int AP = 40;                 // LDS k-stride (shorts): 80B, 16B-aligned
  __shared__ unsigned short a_lds[128 * AP];
  __shared__ unsigned short bh_lds[128 * AP];
  __shared__ unsigned short bl_lds[128 * AP];
  const int tid = threadIdx.x;
  const int wave = tid >> 6;
  const int lane = tid & 63;
  const int quad = lane >> 4;
  const int lrow = lane & 15;
  const int wr = (wave & 1) * 64;
  const int wc = (wave >> 1) * 64;
  const int r0 = blockIdx.x * 128;
  const int n0 = blockIdx.y * 128;

  f32x4 acc[4][4];
#pragma unroll
  for (int i = 0; i < 4; ++i)
#pragma unroll
    for (int j = 0; j < 4; ++j) acc[i][j] = (f32x4){0.f, 0.f, 0.f, 0.f};

  const int srow = tid >> 1;
  const int shalf = tid & 1;
  int agrow = r0 + srow; if (agrow >= M) agrow = M - 1;   // clamp; stores guarded
  const int bgrow = n0 + srow;

  for (int k0 = 0; k0 < K; k0 += 32) {
    {
      const float4* sa = (const float4*)&A[(size_t)agrow * K + k0 + shalf * 16];
      const float4* sh = (const float4*)&Wthi[(size_t)bgrow * K + k0 + shalf * 16];
      const float4* sl = (const float4*)&Wtlo[(size_t)bgrow * K + k0 + shalf * 16];
      float4 va0 = sa[0], va1 = sa[1];
      float4 vh0 = sh[0], vh1 = sh[1];
      float4 vl0 = sl[0], vl1 = sl[1];
      *(float4*)&a_lds[srow * AP + shalf * 16]      = va0;
      *(float4*)&a_lds[srow * AP + shalf * 16 + 8]  = va1;
      *(float4*)&bh_lds[srow * AP + shalf * 16]     = vh0;
      *(float4*)&bh_lds[srow * AP + shalf * 16 + 8] = vh1;
      *(float4*)&bl_lds[srow * AP + shalf * 16]     = vl0;
      *(float4*)&bl_lds[srow * AP + shalf * 16 + 8] = vl1;
    }
    __syncthreads();

    v8s af[4], bh[4], bl[4];
#pragma unroll
    for (int rt = 0; rt < 4; ++rt)
      af[rt] = *(const v8s*)&a_lds[(wr + rt * 16 + lrow) * AP + quad * 8];
#pragma unroll
    for (int ct = 0; ct < 4; ++ct) {
      bh[ct] = *(const v8s*)&bh_lds[(wc + ct * 16 + lrow) * AP + quad * 8];
      bl[ct] = *(const v8s*)&bl_lds[(wc + ct * 16 + lrow) * AP + quad * 8];
    }
#pragma unroll
    for (int rt = 0; rt < 4; ++rt)
#pragma unroll
      for (int ct = 0; ct < 4; ++ct) {
        acc[rt][ct] = __builtin_amdgcn_mfma_f32_16x16x32_bf16(af[rt], bl[ct], acc[rt][ct], 0, 0, 0);
        acc[rt][ct] = __builtin_amdgcn_mfma_f32_16x16x32_bf16(af[rt], bh[ct], acc[rt][ct], 0, 0, 0);
      }
    __syncthreads();
  }

#pragma unroll
  for (int rt = 0; rt < 4; ++rt) {
    int mbase = r0 + wr + rt * 16 + quad * 4;
#pragma unroll
    for (int ct = 0; ct < 4; ++ct) {
      int col = n0 + wc + ct * 16 + lrow;
      float b = HAS_BIAS ? bias[col] : 0.f;
#pragma unroll
      for (int r = 0; r < 4; ++r) {
        int row = mbase + r;
        if (row < M) out[(size_t)row * 256 + col] = f2bf(acc[rt][ct][r] + b);
      }
    }
  }
}

// ---------------- CSR build ----------------
__global__ void degree_kernel(const int* __restrict__ ei, int* __restrict__ deg) {
  int e = blockIdx.x * 256 + threadIdx.x;
  if (e < NE) atomicAdd(&deg[ei[NE + e]], 1);
}

__global__ __launch_bounds__(256) void blocksum_kernel(
    const int* __restrict__ deg, int* __restrict__ bsum) {
  int t = threadIdx.x;
  int i = blockIdx.x * 256 + t;
  int v = (i < NN) ? deg[i] : 0;
#pragma unroll
  for (int off = 32; off; off >>= 1) v += __shfl_down(v, off, 64);
  __shared__ int ws[4];
  if ((t & 63) == 0) ws[t >> 6] = v;
  __syncthreads();
  if (t == 0) bsum[blockIdx.x] = ws[0] + ws[1] + ws[2] + ws[3];
}

__global__ __launch_bounds__(256) void blockscan_kernel(
    const int* __restrict__ bsum, int* __restrict__ bpre, int* __restrict__ rowstart) {
  __shared__ int s[256];
  int t = threadIdx.x;
  int v = (t < NB) ? bsum[t] : 0;
  s[t] = v;
  __syncthreads();
  for (int off = 1; off < 256; off <<= 1) {
    int x = s[t];
    int y = (t >= off) ? s[t - off] : 0;
    __syncthreads();
    s[t] = x + y;
    __syncthreads();
  }
  if (t < NB) bpre[t] = s[t] - v;
  if (t == 255) rowstart[NN] = s[255];
}

__global__ __launch_bounds__(256) void rowstart_kernel(
    const int* __restrict__ deg, const int* __restrict__ bpre,
    int* __restrict__ rowstart, int* __restrict__ cursor) {
  __shared__ int s[256];
  int t = threadIdx.x;
  int i = blockIdx.x * 256 + t;
  int v = (i < NN) ? deg[i] : 0;
  s[t] = v;
  __syncthreads();
  for (int off = 1; off < 256; off <<= 1) {
    int x = s[t];
    int y = (t >= off) ? s[t - off] : 0;
    __syncthreads();
    s[t] = x + y;
    __syncthreads();
  }
  if (i < NN) {
    int rs = bpre[blockIdx.x] + s[t] - v;
    rowstart[i] = rs;
    cursor[i] = rs;
  }
}

__global__ void fill_kernel(const int* __restrict__ ei, const float* __restrict__ ea,
                            int* __restrict__ cursor,
                            int* __restrict__ src_sorted, float* __restrict__ ea_sorted) {
  int e = blockIdx.x * 256 + threadIdx.x;
  if (e < NE) {
    int d = ei[NE + e];
    int pos = atomicAdd(&cursor[d], 1);
    src_sorted[pos] = ei[e];
    ea_sorted[pos] = ea[e];
  }
}

// ---------------- fused GATv2 edge phase: wave per dst node ----------------
// xl/xr are bf16 [N][256]: lane reads 8B (uint2 = 4 bf16) per row -> half the
// gather bytes of f32. 4 edges in flight.
template <bool OUTBF>
__global__ __launch_bounds__(256) void gat_fused_kernel(
    const int* __restrict__ rowstart, const int* __restrict__ src_sorted,
    const float* __restrict__ ea_sorted,
    const unsigned short* __restrict__ xl, const unsigned short* __restrict__ xr,
    const float* __restrict__ we, const float* __restrict__ att,
    const float* __restrict__ bias, float* __restrict__ outf,
    unsigned short* __restrict__ outb) {
  int node = (blockIdx.x * 256 + threadIdx.x) >> 6;
  int lane = threadIdx.x & 63;
  int r0 = rowstart[node], r1 = rowstart[node + 1];
  const uint2* xl2 = (const uint2*)xl;
  uint2 rp = ((const uint2*)xr)[(size_t)node * 64 + lane];
  float4 r = make_float4(bflo(rp.x), bfhi(rp.x), bflo(rp.y), bfhi(rp.y));
  float4 wv = ((const float4*)we)[lane];
  float4 at = ((const float4*)att)[lane];
  float4 acc = make_float4(0.f, 0.f, 0.f, 0.f);
  float denom = 0.f;

  auto edge_step = [&](float eav, uint2 p) {
    float4 a = make_float4(bflo(p.x), bfhi(p.x), bflo(p.y), bfhi(p.y));
    float s0 = a.x + r.x + eav * wv.x;
    float s1 = a.y + r.y + eav * wv.y;
    float s2 = a.z + r.z + eav * wv.z;
    float s3 = a.w + r.w + eav * wv.w;
    s0 = s0 > 0.f ? s0 : 0.2f * s0;
    s1 = s1 > 0.f ? s1 : 0.2f * s1;
    s2 = s2 > 0.f ? s2 : 0.2f * s2;
    s3 = s3 > 0.f ? s3 : 0.2f * s3;
    float p4 = s0 * at.x + s1 * at.y + s2 * at.z + s3 * at.w;
#pragma unroll
    for (int off = 8; off; off >>= 1) p4 += __shfl_xor(p4, off, 16);
    float ex = __expf(p4);
    denom += ex;
    acc.x += ex * a.x; acc.y += ex * a.y; acc.z += ex * a.z; acc.w += ex * a.w;
  };

  int i = r0;
  for (; i + 4 <= r1; i += 4) {           // 4 gathers in flight
    int s0i = src_sorted[i];
    int s1i = src_sorted[i + 1];
    int s2i = src_sorted[i + 2];
    int s3i = src_sorted[i + 3];
    float e0 = ea_sorted[i];
    float e1 = ea_sorted[i + 1];
    float e2 = ea_sorted[i + 2];
    float e3 = ea_sorted[i + 3];
    uint2 p0 = xl2[(size_t)s0i * 64 + lane];
    uint2 p1 = xl2[(size_t)s1i * 64 + lane];
    uint2 p2 = xl2[(size_t)s2i * 64 + lane];
    uint2 p3 = xl2[(size_t)s3i * 64 + lane];
    edge_step(e0, p0);
    edge_step(e1, p1);
    edge_step(e2, p2);
    edge_step(e3, p3);
  }
  for (; i < r1; ++i) {
    edge_step(ea_sorted[i], xl2[(size_t)src_sorted[i] * 64 + lane]);
  }

  float inv = 1.f / (denom + 1e-16f);
  float4 bv = ((const float4*)bias)[lane];
  float4 o;
  o.x = fmaxf(acc.x * inv + bv.x, 0.f);
  o.y = fmaxf(acc.y * inv + bv.y, 0.f);
  o.z = fmaxf(acc.z * inv + bv.z, 0.f);
  o.w = fmaxf(acc.w * inv + bv.w, 0.f);
  if (OUTBF) {
    uint2 pk;
    pk.x = (unsigned)f2bf(o.x) | ((unsigned)f2bf(o.y) << 16);
    pk.y = (unsigned)f2bf(o.z) | ((unsigned)f2bf(o.w) << 16);
    ((uint2*)outb)[(size_t)node * 64 + lane] = pk;
  } else {
    ((float4*)outf)[(size_t)node * 64 + lane] = o;
  }
}

// ---------------- segment bounds via binary search (batch is sorted) ----------------
__global__ void seg_bounds_kernel(const int* __restrict__ batch, int* __restrict__ bounds) {
  int g = threadIdx.x;                 // 0..GG inclusive
  if (g > GG) return;
  int lo = 0, hi = NN;
  while (lo < hi) {
    int mid = (lo + hi) >> 1;
    if (batch[mid] < g) lo = mid + 1; else hi = mid;
  }
  bounds[g] = lo;
}

// ---------------- pooling: block = 64 nodes, 4 row-groups x 64 lanes (float4) ----
__global__ __launch_bounds__(256) void pool_kernel(
    const float* __restrict__ h, const int* __restrict__ batch,
    float* __restrict__ pool) {
  int rg = threadIdx.x >> 6;
  int lane = threadIdx.x & 63;
  int n0 = blockIdx.x * 64;
  const float4* h4 = (const float4*)h;
  float4 acc = make_float4(0.f, 0.f, 0.f, 0.f);
  int cur = -1;
#pragma unroll 4
  for (int i = 0; i < 16; ++i) {
    int n = n0 + rg + 4 * i;
    if (n >= NN) break;
    int b = batch[n];
    if (b != cur) {
      if (cur >= 0) {
        float* p = &pool[cur * 256 + lane * 4];
        atomicAdd(p + 0, acc.x); atomicAdd(p + 1, acc.y);
        atomicAdd(p + 2, acc.z); atomicAdd(p + 3, acc.w);
      }
      cur = b;
      acc = make_float4(0.f, 0.f, 0.f, 0.f);
    }
    float4 v = h4[(size_t)n * 64 + lane];
    acc.x += v.x; acc.y += v.y; acc.z += v.z; acc.w += v.w;
  }
  if (cur >= 0) {
    float* p = &pool[cur * 256 + lane * 4];
    atomicAdd(p + 0, acc.x); atomicAdd(p + 1, acc.y);
    atomicAdd(p + 2, acc.z); atomicAdd(p + 3, acc.w);
  }
}

// ---------------- final MLP: one block (128 thr) per graph ----------------
__global__ __launch_bounds__(128) void mlp_kernel(
    const float* __restrict__ pool, const int* __restrict__ bounds,
    const float* __restrict__ p1w, const float* __restrict__ p1b,
    const float* __restrict__ lng, const float* __restrict__ lnb,
    const float* __restrict__ p2w, const float* __restrict__ p2b,
    const float* __restrict__ hw, const float* __restrict__ hb,
    float* __restrict__ out) {
  __shared__ float sg[256];
  __shared__ float red[128];
  __shared__ float sz[128];
  __shared__ float s2[64];
  int b = blockIdx.x, tid = threadIdx.x;
  float cntf = (float)(bounds[b + 1] - bounds[b]);
  float invc = 1.f / fmaxf(cntf, 1.f);
  for (int i = tid; i < 256; i += 128) sg[i] = pool[b * 256 + i] * invc;
  __syncthreads();
  float z = p1b[tid];
  for (int k = 0; k < 256; ++k) z += sg[k] * p1w[k * 128 + tid];
  red[tid] = z; __syncthreads();
  for (int off = 64; off; off >>= 1) { if (tid < off) red[tid] += red[tid + off]; __syncthreads(); }
  float mu = red[0] * (1.f / 128.f);
  __syncthreads();
  float d = z - mu;
  red[tid] = d * d; __syncthreads();
  for (int off = 64; off; off >>= 1) { if (tid < off) red[tid] += red[tid + off]; __syncthreads(); }
  float var = red[0] * (1.f / 128.f);
  float zn = d * rsqrtf(var + 1e-5f) * lng[tid] + lnb[tid];
  sz[tid] = fmaxf(zn, 0.f);
  __syncthreads();
  if (tid < 64) {
    float a = p2b[tid];
    for (int k = 0; k < 128; ++k) a += sz[k] * p2w[k * 64 + tid];
    s2[tid] = fmaxf(a, 0.f);
  }
  __syncthreads();
  if (tid < 64) {
    float p = s2[tid] * hw[tid];
    for (int off = 32; off; off >>= 1) p += __shfl_down(p, off, 64);
    if (tid == 0) out[b] = p + hb[0];
  }
}

extern "C" void kernel_launch(void* const* d_in, const int* in_sizes, int n_in,
                              void* d_out, int out_size, void* d_ws, size_t ws_size,
                              hipStream_t stream) {
  const float* x      = (const float*)d_in[0];
  const int*   ei     = (const int*)d_in[1];
  const float* ea     = (const float*)d_in[2];
  const int*   batch  = (const int*)d_in[3];
  const float* enc_w  = (const float*)d_in[4];
  const float* enc_b  = (const float*)d_in[5];
  const float* g1_wl  = (const float*)d_in[6];
  const float* g1_bl  = (const float*)d_in[7];
  const float* g1_wr  = (const float*)d_in[8];
  const float* g1_we  = (const float*)d_in[9];
  const float* g1_att = (const float*)d_in[10];
  const float* g1_b   = (const float*)d_in[11];
  const float* g2_wl  = (const float*)d_in[12];
  const float* g2_bl  = (const float*)d_in[13];
  const float* g2_wr  = (const float*)d_in[14];
  const float* g2_we  = (const float*)d_in[15];
  const float* g2_att = (const float*)d_in[16];
  const float* g2_b   = (const float*)d_in[17];
  const float* p1_w   = (const float*)d_in[18];
  const float* p1_b   = (const float*)d_in[19];
  const float* ln_g   = (const float*)d_in[20];
  const float* ln_b   = (const float*)d_in[21];
  const float* p2_w   = (const float*)d_in[22];
  const float* p2_b   = (const float*)d_in[23];
  const float* head_w = (const float*)d_in[24];
  const float* head_b = (const float*)d_in[25];
  float* out = (float*)d_out;

  char* ws = (char*)d_ws;
  size_t off = 0;
  auto alloc = [&](size_t bytes) -> void* {
    void* p = ws + off;
    off = (off + bytes + 255) & ~(size_t)255;
    return p;
  };
  unsigned short* xl   = (unsigned short*)alloc((size_t)NN * HC * 2);
  unsigned short* xr   = (unsigned short*)alloc((size_t)NN * HC * 2);
  float* hbuf      = (float*)alloc((size_t)NN * HC * 4);
  unsigned short* h0   = (unsigned short*)alloc((size_t)NN * 64 * 2);
  unsigned short* hb16 = (unsigned short*)alloc((size_t)NN * HC * 2);
  unsigned short* wt1l_hi = (unsigned short*)alloc((size_t)64 * 256 * 2);
  unsigned short* wt1l_lo = (unsigned short*)alloc((size_t)64 * 256 * 2);
  unsigned short* wt1r_hi = (unsigned short*)alloc((size_t)64 * 256 * 2);
  unsigned short* wt1r_lo = (unsigned short*)alloc((size_t)64 * 256 * 2);
  unsigned short* wt2l_hi = (unsigned short*)alloc((size_t)256 * 256 * 2);
  unsigned short* wt2l_lo = (unsigned short*)alloc((size_t)256 * 256 * 2);
  unsigned short* wt2r_hi = (unsigned short*)alloc((size_t)256 * 256 * 2);
  unsigned short* wt2r_lo = (unsigned short*)alloc((size_t)256 * 256 * 2);
  float* pool      = (float*)alloc((size_t)GG * HC * 4);
  int*   deg       = (int*)alloc((size_t)NN * 4);
  int*   rowstart  = (int*)alloc((size_t)(NN + 1) * 4);
  int*   cursor    = (int*)alloc((size_t)NN * 4);
  int*   bsum      = (int*)alloc((size_t)NB * 4);
  int*   bpre      = (int*)alloc((size_t)NB * 4);
  int*   src_sorted= (int*)alloc((size_t)NE * 4);
  float* ea_sorted = (float*)alloc((size_t)NE * 4);
  int*   bounds    = (int*)alloc((size_t)(GG + 1) * 4);

  hipMemsetAsync(deg, 0, (size_t)NN * 4, stream);
  hipMemsetAsync(pool, 0, (size_t)GG * HC * 4, stream);

  // encoder (bf16 out) + weight prep
  encoder_kernel<<<NN * 64 / 256, 256, 0, stream>>>(x, enc_w, enc_b, h0);
  wconv_kernel<<<64, 256, 0, stream>>>(g1_wl, 64, wt1l_hi, wt1l_lo);
  wconv_kernel<<<64, 256, 0, stream>>>(g1_wr, 64, wt1r_hi, wt1r_lo);
  wconv_kernel<<<256, 256, 0, stream>>>(g2_wl, 256, wt2l_hi, wt2l_lo);
  wconv_kernel<<<256, 256, 0, stream>>>(g2_wr, 256, wt2r_hi, wt2r_lo);

  // CSR build: degree -> hierarchical scan -> fill
  degree_kernel<<<(NE + 255) / 256, 256, 0, stream>>>(ei, deg);
  blocksum_kernel<<<NB, 256, 0, stream>>>(deg, bsum);
  blockscan_kernel<<<1, 256, 0, stream>>>(bsum, bpre, rowstart);
  rowstart_kernel<<<NB, 256, 0, stream>>>(deg, bpre, rowstart, cursor);
  fill_kernel<<<(NE + 255) / 256, 256, 0, stream>>>(ei, ea, cursor, src_sorted, ea_sorted);

  // graph segment bounds (batch is sorted)
  seg_bounds_kernel<<<1, GG + 1, 0, stream>>>(batch, bounds);

  dim3 mmg((NN + 127) / 128, 2);   // 391 x 2 blocks

  // ---- GAT layer 1 (K=64) ----
  matmul_mfma_kernel<64, true><<<mmg, 256, 0, stream>>>(h0, wt1l_hi, wt1l_lo, g1_bl, xl, NN);
  matmul_mfma_kernel<64, false><<<mmg, 256, 0, stream>>>(h0, wt1r_hi, wt1r_lo, nullptr, xr, NN);
  gat_fused_kernel<true><<<NN / 4, 256, 0, stream>>>(rowstart, src_sorted, ea_sorted,
                                                     xl, xr, g1_we, g1_att, g1_b,
                                                     nullptr, hb16);

  // ---- GAT layer 2 (K=256) ----
  matmul_mfma_kernel<256, true><<<mmg, 256, 0, stream>>>(hb16, wt2l_hi, wt2l_lo, g2_bl, xl, NN);
  matmul_mfma_kernel<256, false><<<mmg, 256, 0, stream>>>(hb16, wt2r_hi, wt2r_lo, nullptr, xr, NN);
  gat_fused_kernel<false><<<NN / 4, 256, 0, stream>>>(rowstart, src_sorted, ea_sorted,
                                                      xl, xr, g2_we, g2_att, g2_b,
                                                      hbuf, nullptr);

  // ---- pooling + MLP head ----
  pool_kernel<<<(NN + 63) / 64, 256, 0, stream>>>(hbuf, batch, pool);
  mlp_kernel<<<GG, 128, 0, stream>>>(pool, bounds, p1_w, p1_b, ln_g, ln_b,
                                     p2_w, p2_b, head_w, head_b, out);
}

// Round 15
// 393.838 us; speedup vs baseline: 4.0118x; 1.0128x over previous
//
#include <hip/hip_runtime.h>
#include <hip/hip_bf16.h>
#include <math.h>

#define NN 50000     // nodes
#define NE 400000    // edges
#define HH 4         // heads
#define CC 64        // per-head dim
#define HC 256       // H*C
#define GG 64        // graphs
#define NB 196       // scan blocks: ceil(NN/256)

typedef short v8s __attribute__((ext_vector_type(8)));
typedef float f32x4 __attribute__((ext_vector_type(4)));

static __device__ inline unsigned short f2bf(float v) {
  __hip_bfloat16 b = __float2bfloat16(v);
  return *reinterpret_cast<unsigned short*>(&b);
}
// packed bf16 pair -> f32 (bf16 value = bit pattern << 16)
static __device__ inline float bflo(unsigned u) { return __uint_as_float(u << 16); }
static __device__ inline float bfhi(unsigned u) { return __uint_as_float(u & 0xffff0000u); }

// ---------------- encoder: h0 = relu(x @ enc_w + enc_b) -> bf16 ----------------
__global__ __launch_bounds__(256) void encoder_kernel(
    const float* __restrict__ x, const float* __restrict__ w,
    const float* __restrict__ b, unsigned short* __restrict__ h0) {
  int idx = blockIdx.x * 256 + threadIdx.x;   // N*64 threads
  int node = idx >> 6, col = idx & 63;
  const float* xr = x + node * 8;
  float acc = b[col];
#pragma unroll
  for (int k = 0; k < 8; ++k) acc += xr[k] * w[k * 64 + col];
  h0[idx] = f2bf(fmaxf(acc, 0.f));
}

// ---- W prep: W[K,256] f32 -> Wt bf16 [256][K] (k-contiguous rows) ----
// Single bf16 (no hi/lo split): the matmul output is rounded to bf16 anyway,
// and W's random-sign rounding error averages to ~0.4%/sqrt(K) in the dot —
// below the 0.4% output rounding. Split-W was precision the epilogue discarded.
__global__ __launch_bounds__(256) void wconv_kernel(
    const float* __restrict__ W, int K, unsigned short* __restrict__ Wt) {
  int idx = blockIdx.x * 256 + threadIdx.x;
  if (idx >= K * 256) return;
  int k = idx >> 8, n = idx & 255;
  Wt[n * K + k] = f2bf(W[idx]);
}

// ---------------- MFMA matmul: out(bf16)[M,256] = A(bf16) @ W(bf16) (+bias) ----------
// Block 128x128, 4 waves (2x2), each wave 64x64 = 4x4 tiles of 16x16x32.
// LDS-staged A/B; 1 MFMA per tile per chunk; epilogue rounds to bf16.
template <int K, bool HAS_BIAS>
__global__ __launch_bounds__(256) void matmul_mfma_kernel(
    const unsigned short* __restrict__ A, const unsigned short* __restrict__ Wt,
    const float* __restrict__ bias, unsigned short* __restrict__ out, int M) {
  constexpr int AP = 40;                 // LDS k-stride (shorts): 80B, 16B-aligned
  __shared__ unsigned short a_lds[128 * AP];
  __shared__ unsigned short b_lds[128 * AP];
  const int tid = threadIdx.x;
  const int wave = tid >> 6;
  const int lane = tid & 63;
  const int quad = lane >> 4;
  const int lrow = lane & 15;
  const int wr = (wave & 1) * 64;
  const int wc = (wave >> 1) * 64;
  const int r0 = blockIdx.x * 128;
  const int n0 = blockIdx.y * 128;

  f32x4 acc[4][4];
#pragma unroll
  for (int i = 0; i < 4; ++i)
#pragma unroll
    for (int j = 0; j < 4; ++j) acc[i][j] = (f32x4){0.f, 0.f, 0.f, 0.f};

  const int srow = tid >> 1;
  const int shalf = tid & 1;
  int agrow = r0 + srow; if (agrow >= M) agrow = M - 1;   // clamp; stores guarded
  const int bgrow = n0 + srow;

  for (int k0 = 0; k0 < K; k0 += 32) {
    {
      const float4* sa = (const float4*)&A[(size_t)agrow * K + k0 + shalf * 16];
      const float4* sb = (const float4*)&Wt[(size_t)bgrow * K + k0 + shalf * 16];
      float4 va0 = sa[0], va1 = sa[1];
      float4 vb0 = sb[0], vb1 = sb[1];
      *(float4*)&a_lds[srow * AP + shalf * 16]     = va0;
      *(float4*)&a_lds[srow * AP + shalf * 16 + 8] = va1;
      *(float4*)&b_lds[srow * AP + shalf * 16]     = vb0;
      *(float4*)&b_lds[srow * AP + shalf * 16 + 8] = vb1;
    }
    __syncthreads();

    v8s af[4], bf[4];
#pragma unroll
    for (int rt = 0; rt < 4; ++rt)
      af[rt] = *(const v8s*)&a_lds[(wr + rt * 16 + lrow) * AP + quad * 8];
#pragma unroll
    for (int ct = 0; ct < 4; ++ct)
      bf[ct] = *(const v8s*)&b_lds[(wc + ct * 16 + lrow) * AP + quad * 8];
#pragma unroll
    for (int rt = 0; rt < 4; ++rt)
#pragma unroll
      for (int ct = 0; ct < 4; ++ct)
        acc[rt][ct] = __builtin_amdgcn_mfma_f32_16x16x32_bf16(af[rt], bf[ct], acc[rt][ct], 0, 0, 0);
    __syncthreads();
  }

#pragma unroll
  for (int rt = 0; rt < 4; ++rt) {
    int mbase = r0 + wr + rt * 16 + quad * 4;
#pragma unroll
    for (int ct = 0; ct < 4; ++ct) {
      int col = n0 + wc + ct * 16 + lrow;
      float b = HAS_BIAS ? bias[col] : 0.f;
#pragma unroll
      for (int r = 0; r < 4; ++r) {
        int row = mbase + r;
        if (row < M) out[(size_t)row * 256 + col] = f2bf(acc[rt][ct][r] + b);
      }
    }
  }
}

// ---------------- CSR build ----------------
__global__ void degree_kernel(const int* __restrict__ ei, int* __restrict__ deg) {
  int e = blockIdx.x * 256 + threadIdx.x;
  if (e < NE) atomicAdd(&deg[ei[NE + e]], 1);
}

__global__ __launch_bounds__(256) void blocksum_kernel(
    const int* __restrict__ deg, int* __restrict__ bsum) {
  int t = threadIdx.x;
  int i = blockIdx.x * 256 + t;
  int v = (i < NN) ? deg[i] : 0;
#pragma unroll
  for (int off = 32; off; off >>= 1) v += __shfl_down(v, off, 64);
  __shared__ int ws[4];
  if ((t & 63) == 0) ws[t >> 6] = v;
  __syncthreads();
  if (t == 0) bsum[blockIdx.x] = ws[0] + ws[1] + ws[2] + ws[3];
}

__global__ __launch_bounds__(256) void blockscan_kernel(
    const int* __restrict__ bsum, int* __restrict__ bpre, int* __restrict__ rowstart) {
  __shared__ int s[256];
  int t = threadIdx.x;
  int v = (t < NB) ? bsum[t] : 0;
  s[t] = v;
  __syncthreads();
  for (int off = 1; off < 256; off <<= 1) {
    int x = s[t];
    int y = (t >= off) ? s[t - off] : 0;
    __syncthreads();
    s[t] = x + y;
    __syncthreads();
  }
  if (t < NB) bpre[t] = s[t] - v;
  if (t == 255) rowstart[NN] = s[255];
}

__global__ __launch_bounds__(256) void rowstart_kernel(
    const int* __restrict__ deg, const int* __restrict__ bpre,
    int* __restrict__ rowstart, int* __restrict__ cursor) {
  __shared__ int s[256];
  int t = threadIdx.x;
  int i = blockIdx.x * 256 + t;
  int v = (i < NN) ? deg[i] : 0;
  s[t] = v;
  __syncthreads();
  for (int off = 1; off < 256; off <<= 1) {
    int x = s[t];
    int y = (t >= off) ? s[t - off] : 0;
    __syncthreads();
    s[t] = x + y;
    __syncthreads();
  }
  if (i < NN) {
    int rs = bpre[blockIdx.x] + s[t] - v;
    rowstart[i] = rs;
    cursor[i] = rs;
  }
}

__global__ void fill_kernel(const int* __restrict__ ei, const float* __restrict__ ea,
                            int* __restrict__ cursor,
                            int* __restrict__ src_sorted, float* __restrict__ ea_sorted) {
  int e = blockIdx.x * 256 + threadIdx.x;
  if (e < NE) {
    int d = ei[NE + e];
    int pos = atomicAdd(&cursor[d], 1);
    src_sorted[pos] = ei[e];
    ea_sorted[pos] = ea[e];
  }
}

// ---------------- fused GATv2 edge phase: wave per dst node ----------------
// xl/xr are bf16 [N][256]: lane reads 8B (uint2 = 4 bf16) per row. 4 edges in flight.
template <bool OUTBF>
__global__ __launch_bounds__(256) void gat_fused_kernel(
    const int* __restrict__ rowstart, const int* __restrict__ src_sorted,
    const float* __restrict__ ea_sorted,
    const unsigned short* __restrict__ xl, const unsigned short* __restrict__ xr,
    const float* __restrict__ we, const float* __restrict__ att,
    const float* __restrict__ bias, float* __restrict__ outf,
    unsigned short* __restrict__ outb) {
  int node = (blockIdx.x * 256 + threadIdx.x) >> 6;
  int lane = threadIdx.x & 63;
  int r0 = rowstart[node], r1 = rowstart[node + 1];
  const uint2* xl2 = (const uint2*)xl;
  uint2 rp = ((const uint2*)xr)[(size_t)node * 64 + lane];
  float4 r = make_float4(bflo(rp.x), bfhi(rp.x), bflo(rp.y), bfhi(rp.y));
  float4 wv = ((const float4*)we)[lane];
  float4 at = ((const float4*)att)[lane];
  float4 acc = make_float4(0.f, 0.f, 0.f, 0.f);
  float denom = 0.f;

  auto edge_step = [&](float eav, uint2 p) {
    float4 a = make_float4(bflo(p.x), bfhi(p.x), bflo(p.y), bfhi(p.y));
    float s0 = a.x + r.x + eav * wv.x;
    float s1 = a.y + r.y + eav * wv.y;
    float s2 = a.z + r.z + eav * wv.z;
    float s3 = a.w + r.w + eav * wv.w;
    s0 = s0 > 0.f ? s0 : 0.2f * s0;
    s1 = s1 > 0.f ? s1 : 0.2f * s1;
    s2 = s2 > 0.f ? s2 : 0.2f * s2;
    s3 = s3 > 0.f ? s3 : 0.2f * s3;
    float p4 = s0 * at.x + s1 * at.y + s2 * at.z + s3 * at.w;
#pragma unroll
    for (int off = 8; off; off >>= 1) p4 += __shfl_xor(p4, off, 16);
    float ex = __expf(p4);
    denom += ex;
    acc.x += ex * a.x; acc.y += ex * a.y; acc.z += ex * a.z; acc.w += ex * a.w;
  };

  int i = r0;
  for (; i + 4 <= r1; i += 4) {           // 4 gathers in flight
    int s0i = src_sorted[i];
    int s1i = src_sorted[i + 1];
    int s2i = src_sorted[i + 2];
    int s3i = src_sorted[i + 3];
    float e0 = ea_sorted[i];
    float e1 = ea_sorted[i + 1];
    float e2 = ea_sorted[i + 2];
    float e3 = ea_sorted[i + 3];
    uint2 p0 = xl2[(size_t)s0i * 64 + lane];
    uint2 p1 = xl2[(size_t)s1i * 64 + lane];
    uint2 p2 = xl2[(size_t)s2i * 64 + lane];
    uint2 p3 = xl2[(size_t)s3i * 64 + lane];
    edge_step(e0, p0);
    edge_step(e1, p1);
    edge_step(e2, p2);
    edge_step(e3, p3);
  }
  for (; i < r1; ++i) {
    edge_step(ea_sorted[i], xl2[(size_t)src_sorted[i] * 64 + lane]);
  }

  float inv = 1.f / (denom + 1e-16f);
  float4 bv = ((const float4*)bias)[lane];
  float4 o;
  o.x = fmaxf(acc.x * inv + bv.x, 0.f);
  o.y = fmaxf(acc.y * inv + bv.y, 0.f);
  o.z = fmaxf(acc.z * inv + bv.z, 0.f);
  o.w = fmaxf(acc.w * inv + bv.w, 0.f);
  if (OUTBF) {
    uint2 pk;
    pk.x = (unsigned)f2bf(o.x) | ((unsigned)f2bf(o.y) << 16);
    pk.y = (unsigned)f2bf(o.z) | ((unsigned)f2bf(o.w) << 16);
    ((uint2*)outb)[(size_t)node * 64 + lane] = pk;
  } else {
    ((float4*)outf)[(size_t)node * 64 + lane] = o;
  }
}

// ---------------- segment bounds via binary search (batch is sorted) ----------------
__global__ void seg_bounds_kernel(const int* __restrict__ batch, int* __restrict__ bounds) {
  int g = threadIdx.x;                 // 0..GG inclusive
  if (g > GG) return;
  int lo = 0, hi = NN;
  while (lo < hi) {
    int mid = (lo + hi) >> 1;
    if (batch[mid] < g) lo = mid + 1; else hi = mid;
  }
  bounds[g] = lo;
}

// ---------------- pooling: block = 64 nodes, 4 row-groups x 64 lanes (float4) ----
__global__ __launch_bounds__(256) void pool_kernel(
    const float* __restrict__ h, const int* __restrict__ batch,
    float* __restrict__ pool) {
  int rg = threadIdx.x >> 6;
  int lane = threadIdx.x & 63;
  int n0 = blockIdx.x * 64;
  const float4* h4 = (const float4*)h;
  float4 acc = make_float4(0.f, 0.f, 0.f, 0.f);
  int cur = -1;
#pragma unroll 4
  for (int i = 0; i < 16; ++i) {
    int n = n0 + rg + 4 * i;
    if (n >= NN) break;
    int b = batch[n];
    if (b != cur) {
      if (cur >= 0) {
        float* p = &pool[cur * 256 + lane * 4];
        atomicAdd(p + 0, acc.x); atomicAdd(p + 1, acc.y);
        atomicAdd(p + 2, acc.z); atomicAdd(p + 3, acc.w);
      }
      cur = b;
      acc = make_float4(0.f, 0.f, 0.f, 0.f);
    }
    float4 v = h4[(size_t)n * 64 + lane];
    acc.x += v.x; acc.y += v.y; acc.z += v.z; acc.w += v.w;
  }
  if (cur >= 0) {
    float* p = &pool[cur * 256 + lane * 4];
    atomicAdd(p + 0, acc.x); atomicAdd(p + 1, acc.y);
    atomicAdd(p + 2, acc.z); atomicAdd(p + 3, acc.w);
  }
}

// ---------------- final MLP: one block (128 thr) per graph ----------------
__global__ __launch_bounds__(128) void mlp_kernel(
    const float* __restrict__ pool, const int* __restrict__ bounds,
    const float* __restrict__ p1w, const float* __restrict__ p1b,
    const float* __restrict__ lng, const float* __restrict__ lnb,
    const float* __restrict__ p2w, const float* __restrict__ p2b,
    const float* __restrict__ hw, const float* __restrict__ hb,
    float* __restrict__ out) {
  __shared__ float sg[256];
  __shared__ float red[128];
  __shared__ float sz[128];
  __shared__ float s2[64];
  int b = blockIdx.x, tid = threadIdx.x;
  float cntf = (float)(bounds[b + 1] - bounds[b]);
  float invc = 1.f / fmaxf(cntf, 1.f);
  for (int i = tid; i < 256; i += 128) sg[i] = pool[b * 256 + i] * invc;
  __syncthreads();
  float z = p1b[tid];
  for (int k = 0; k < 256; ++k) z += sg[k] * p1w[k * 128 + tid];
  red[tid] = z; __syncthreads();
  for (int off = 64; off; off >>= 1) { if (tid < off) red[tid] += red[tid + off]; __syncthreads(); }
  float mu = red[0] * (1.f / 128.f);
  __syncthreads();
  float d = z - mu;
  red[tid] = d * d; __syncthreads();
  for (int off = 64; off; off >>= 1) { if (tid < off) red[tid] += red[tid + off]; __syncthreads(); }
  float var = red[0] * (1.f / 128.f);
  float zn = d * rsqrtf(var + 1e-5f) * lng[tid] + lnb[tid];
  sz[tid] = fmaxf(zn, 0.f);
  __syncthreads();
  if (tid < 64) {
    float a = p2b[tid];
    for (int k = 0; k < 128; ++k) a += sz[k] * p2w[k * 64 + tid];
    s2[tid] = fmaxf(a, 0.f);
  }
  __syncthreads();
  if (tid < 64) {
    float p = s2[tid] * hw[tid];
    for (int off = 32; off; off >>= 1) p += __shfl_down(p, off, 64);
    if (tid == 0) out[b] = p + hb[0];
  }
}

extern "C" void kernel_launch(void* const* d_in, const int* in_sizes, int n_in,
                              void* d_out, int out_size, void* d_ws, size_t ws_size,
                              hipStream_t stream) {
  const float* x      = (const float*)d_in[0];
  const int*   ei     = (const int*)d_in[1];
  const float* ea     = (const float*)d_in[2];
  const int*   batch  = (const int*)d_in[3];
  const float* enc_w  = (const float*)d_in[4];
  const float* enc_b  = (const float*)d_in[5];
  const float* g1_wl  = (const float*)d_in[6];
  const float* g1_bl  = (const float*)d_in[7];
  const float* g1_wr  = (const float*)d_in[8];
  const float* g1_we  = (const float*)d_in[9];
  const float* g1_att = (const float*)d_in[10];
  const float* g1_b   = (const float*)d_in[11];
  const float* g2_wl  = (const float*)d_in[12];
  const float* g2_bl  = (const float*)d_in[13];
  const float* g2_wr  = (const float*)d_in[14];
  const float* g2_we  = (const float*)d_in[15];
  const float* g2_att = (const float*)d_in[16];
  const float* g2_b   = (const float*)d_in[17];
  const float* p1_w   = (const float*)d_in[18];
  const float* p1_b   = (const float*)d_in[19];
  const float* ln_g   = (const float*)d_in[20];
  const float* ln_b   = (const float*)d_in[21];
  const float* p2_w   = (const float*)d_in[22];
  const float* p2_b   = (const float*)d_in[23];
  const float* head_w = (const float*)d_in[24];
  const float* head_b = (const float*)d_in[25];
  float* out = (float*)d_out;

  char* ws = (char*)d_ws;
  size_t off = 0;
  auto alloc = [&](size_t bytes) -> void* {
    void* p = ws + off;
    off = (off + bytes + 255) & ~(size_t)255;
    return p;
  };
  unsigned short* xl   = (unsigned short*)alloc((size_t)NN * HC * 2);
  unsigned short* xr   = (unsigned short*)alloc((size_t)NN * HC * 2);
  float* hbuf      = (float*)alloc((size_t)NN * HC * 4);
  unsigned short* h0   = (unsigned short*)alloc((size_t)NN * 64 * 2);
  unsigned short* hb16 = (unsigned short*)alloc((size_t)NN * HC * 2);
  unsigned short* wt1l = (unsigned short*)alloc((size_t)64 * 256 * 2);
  unsigned short* wt1r = (unsigned short*)alloc((size_t)64 * 256 * 2);
  unsigned short* wt2l = (unsigned short*)alloc((size_t)256 * 256 * 2);
  unsigned short* wt2r = (unsigned short*)alloc((size_t)256 * 256 * 2);
  float* pool      = (float*)alloc((size_t)GG * HC * 4);
  int*   deg       = (int*)alloc((size_t)NN * 4);
  int*   rowstart  = (int*)alloc((size_t)(NN + 1) * 4);
  int*   cursor    = (int*)alloc((size_t)NN * 4);
  int*   bsum      = (int*)alloc((size_t)NB * 4);
  int*   bpre      = (int*)alloc((size_t)NB * 4);
  int*   src_sorted= (int*)alloc((size_t)NE * 4);
  float* ea_sorted = (float*)alloc((size_t)NE * 4);
  int*   bounds    = (int*)alloc((size_t)(GG + 1) * 4);

  hipMemsetAsync(deg, 0, (size_t)NN * 4, stream);
  hipMemsetAsync(pool, 0, (size_t)GG * HC * 4, stream);

  // encoder (bf16 out) + weight prep
  encoder_kernel<<<NN * 64 / 256, 256, 0, stream>>>(x, enc_w, enc_b, h0);
  wconv_kernel<<<64, 256, 0, stream>>>(g1_wl, 64, wt1l);
  wconv_kernel<<<64, 256, 0, stream>>>(g1_wr, 64, wt1r);
  wconv_kernel<<<256, 256, 0, stream>>>(g2_wl, 256, wt2l);
  wconv_kernel<<<256, 256, 0, stream>>>(g2_wr, 256, wt2r);

  // CSR build: degree -> hierarchical scan -> fill
  degree_kernel<<<(NE + 255) / 256, 256, 0, stream>>>(ei, deg);
  blocksum_kernel<<<NB, 256, 0, stream>>>(deg, bsum);
  blockscan_kernel<<<1, 256, 0, stream>>>(bsum, bpre, rowstart);
  rowstart_kernel<<<NB, 256, 0, stream>>>(deg, bpre, rowstart, cursor);
  fill_kernel<<<(NE + 255) / 256, 256, 0, stream>>>(ei, ea, cursor, src_sorted, ea_sorted);

  // graph segment bounds (batch is sorted)
  seg_bounds_kernel<<<1, GG + 1, 0, stream>>>(batch, bounds);

  dim3 mmg((NN + 127) / 128, 2);   // 391 x 2 blocks

  // ---- GAT layer 1 (K=64) ----
  matmul_mfma_kernel<64, true><<<mmg, 256, 0, stream>>>(h0, wt1l, g1_bl, xl, NN);
  matmul_mfma_kernel<64, false><<<mmg, 256, 0, stream>>>(h0, wt1r, nullptr, xr, NN);
  gat_fused_kernel<true><<<NN / 4, 256, 0, stream>>>(rowstart, src_sorted, ea_sorted,
                                                     xl, xr, g1_we, g1_att, g1_b,
                                                     nullptr, hb16);

  // ---- GAT layer 2 (K=256) ----
  matmul_mfma_kernel<256, true><<<mmg, 256, 0, stream>>>(hb16, wt2l, g2_bl, xl, NN);
  matmul_mfma_kernel<256, false><<<mmg, 256, 0, stream>>>(hb16, wt2r, nullptr, xr, NN);
  gat_fused_kernel<false><<<NN / 4, 256, 0, stream>>>(rowstart, src_sorted, ea_sorted,
                                                      xl, xr, g2_we, g2_att, g2_b,
                                                      hbuf, nullptr);

  // ---- pooling + MLP head ----
  pool_kernel<<<(NN + 63) / 64, 256, 0, stream>>>(hbuf, batch, pool);
  mlp_kernel<<<GG, 128, 0, stream>>>(pool, bounds, p1_w, p1_b, ln_g, ln_b,
                                     p2_w, p2_b, head_w, head_b, out);
}

// Round 16
// 371.913 us; speedup vs baseline: 4.2483x; 1.0590x over previous
//
#include <hip/hip_runtime.h>
#include <hip/hip_bf16.h>
#include <math.h>

#define NN 50000     // nodes
#define NE 400000    // edges
#define HH 4         // heads
#define CC 64        // per-head dim
#define HC 256       // H*C
#define GG 64        // graphs
#define NB 196       // scan blocks: ceil(NN/256)

typedef short v8s __attribute__((ext_vector_type(8)));
typedef float f32x4 __attribute__((ext_vector_type(4)));

static __device__ inline unsigned short f2bf(float v) {
  __hip_bfloat16 b = __float2bfloat16(v);
  return *reinterpret_cast<unsigned short*>(&b);
}
// packed bf16 pair -> f32 (bf16 value = bit pattern << 16)
static __device__ inline float bflo(unsigned u) { return __uint_as_float(u << 16); }
static __device__ inline float bfhi(unsigned u) { return __uint_as_float(u & 0xffff0000u); }

// ---------------- encoder: h0 = relu(x @ enc_w + enc_b) -> bf16 ----------------
__global__ __launch_bounds__(256) void encoder_kernel(
    const float* __restrict__ x, const float* __restrict__ w,
    const float* __restrict__ b, unsigned short* __restrict__ h0) {
  int idx = blockIdx.x * 256 + threadIdx.x;   // N*64 threads
  int node = idx >> 6, col = idx & 63;
  const float* xr = x + node * 8;
  float acc = b[col];
#pragma unroll
  for (int k = 0; k < 8; ++k) acc += xr[k] * w[k * 64 + col];
  h0[idx] = f2bf(fmaxf(acc, 0.f));
}

// ---- W prep: W[K,256] f32 -> Wt bf16 [256][K] (k-contiguous rows) ----
__global__ __launch_bounds__(256) void wconv_kernel(
    const float* __restrict__ W, int K, unsigned short* __restrict__ Wt) {
  int idx = blockIdx.x * 256 + threadIdx.x;
  if (idx >= K * 256) return;
  int k = idx >> 8, n = idx & 255;
  Wt[n * K + k] = f2bf(W[idx]);
}

// ---------------- MFMA matmul: out(bf16)[M,256] = A(bf16) @ W(bf16) (+bias) ----------
// Block 128x128, 4 waves (2x2), each wave 64x64 = 4x4 tiles of 16x16x32.
template <int K, bool HAS_BIAS>
__global__ __launch_bounds__(256) void matmul_mfma_kernel(
    const unsigned short* __restrict__ A, const unsigned short* __restrict__ Wt,
    const float* __restrict__ bias, unsigned short* __restrict__ out, int M) {
  constexpr int AP = 40;                 // LDS k-stride (shorts): 80B, 16B-aligned
  __shared__ unsigned short a_lds[128 * AP];
  __shared__ unsigned short b_lds[128 * AP];
  const int tid = threadIdx.x;
  const int wave = tid >> 6;
  const int lane = tid & 63;
  const int quad = lane >> 4;
  const int lrow = lane & 15;
  const int wr = (wave & 1) * 64;
  const int wc = (wave >> 1) * 64;
  const int r0 = blockIdx.x * 128;
  const int n0 = blockIdx.y * 128;

  f32x4 acc[4][4];
#pragma unroll
  for (int i = 0; i < 4; ++i)
#pragma unroll
    for (int j = 0; j < 4; ++j) acc[i][j] = (f32x4){0.f, 0.f, 0.f, 0.f};

  const int srow = tid >> 1;
  const int shalf = tid & 1;
  int agrow = r0 + srow; if (agrow >= M) agrow = M - 1;   // clamp; stores guarded
  const int bgrow = n0 + srow;

  for (int k0 = 0; k0 < K; k0 += 32) {
    {
      const float4* sa = (const float4*)&A[(size_t)agrow * K + k0 + shalf * 16];
      const float4* sb = (const float4*)&Wt[(size_t)bgrow * K + k0 + shalf * 16];
      float4 va0 = sa[0], va1 = sa[1];
      float4 vb0 = sb[0], vb1 = sb[1];
      *(float4*)&a_lds[srow * AP + shalf * 16]     = va0;
      *(float4*)&a_lds[srow * AP + shalf * 16 + 8] = va1;
      *(float4*)&b_lds[srow * AP + shalf * 16]     = vb0;
      *(float4*)&b_lds[srow * AP + shalf * 16 + 8] = vb1;
    }
    __syncthreads();

    v8s af[4], bf[4];
#pragma unroll
    for (int rt = 0; rt < 4; ++rt)
      af[rt] = *(const v8s*)&a_lds[(wr + rt * 16 + lrow) * AP + quad * 8];
#pragma unroll
    for (int ct = 0; ct < 4; ++ct)
      bf[ct] = *(const v8s*)&b_lds[(wc + ct * 16 + lrow) * AP + quad * 8];
#pragma unroll
    for (int rt = 0; rt < 4; ++rt)
#pragma unroll
      for (int ct = 0; ct < 4; ++ct)
        acc[rt][ct] = __builtin_amdgcn_mfma_f32_16x16x32_bf16(af[rt], bf[ct], acc[rt][ct], 0, 0, 0);
    __syncthreads();
  }

#pragma unroll
  for (int rt = 0; rt < 4; ++rt) {
    int mbase = r0 + wr + rt * 16 + quad * 4;
#pragma unroll
    for (int ct = 0; ct < 4; ++ct) {
      int col = n0 + wc + ct * 16 + lrow;
      float b = HAS_BIAS ? bias[col] : 0.f;
#pragma unroll
      for (int r = 0; r < 4; ++r) {
        int row = mbase + r;
        if (row < M) out[(size_t)row * 256 + col] = f2bf(acc[rt][ct][r] + b);
      }
    }
  }
}

// ---------------- CSR build ----------------
__global__ void degree_kernel(const int* __restrict__ ei, int* __restrict__ deg) {
  int e = blockIdx.x * 256 + threadIdx.x;
  if (e < NE) atomicAdd(&deg[ei[NE + e]], 1);
}

__global__ __launch_bounds__(256) void blocksum_kernel(
    const int* __restrict__ deg, int* __restrict__ bsum) {
  int t = threadIdx.x;
  int i = blockIdx.x * 256 + t;
  int v = (i < NN) ? deg[i] : 0;
#pragma unroll
  for (int off = 32; off; off >>= 1) v += __shfl_down(v, off, 64);
  __shared__ int ws[4];
  if ((t & 63) == 0) ws[t >> 6] = v;
  __syncthreads();
  if (t == 0) bsum[blockIdx.x] = ws[0] + ws[1] + ws[2] + ws[3];
}

__global__ __launch_bounds__(256) void blockscan_kernel(
    const int* __restrict__ bsum, int* __restrict__ bpre, int* __restrict__ rowstart) {
  __shared__ int s[256];
  int t = threadIdx.x;
  int v = (t < NB) ? bsum[t] : 0;
  s[t] = v;
  __syncthreads();
  for (int off = 1; off < 256; off <<= 1) {
    int x = s[t];
    int y = (t >= off) ? s[t - off] : 0;
    __syncthreads();
    s[t] = x + y;
    __syncthreads();
  }
  if (t < NB) bpre[t] = s[t] - v;
  if (t == 255) rowstart[NN] = s[255];
}

__global__ __launch_bounds__(256) void rowstart_kernel(
    const int* __restrict__ deg, const int* __restrict__ bpre,
    int* __restrict__ rowstart, int* __restrict__ cursor) {
  __shared__ int s[256];
  int t = threadIdx.x;
  int i = blockIdx.x * 256 + t;
  int v = (i < NN) ? deg[i] : 0;
  s[t] = v;
  __syncthreads();
  for (int off = 1; off < 256; off <<= 1) {
    int x = s[t];
    int y = (t >= off) ? s[t - off] : 0;
    __syncthreads();
    s[t] = x + y;
    __syncthreads();
  }
  if (i < NN) {
    int rs = bpre[blockIdx.x] + s[t] - v;
    rowstart[i] = rs;
    cursor[i] = rs;
  }
}

// CSR fill: single int2 (src, ea-bits) per edge -> one aligned 8B scatter store
// (was two 4B stores into two arrays) and one combined load in gat_fused.
__global__ void fill_kernel(const int* __restrict__ ei, const float* __restrict__ ea,
                            int* __restrict__ cursor, int2* __restrict__ edges) {
  int e = blockIdx.x * 256 + threadIdx.x;
  if (e < NE) {
    int d = ei[NE + e];
    int pos = atomicAdd(&cursor[d], 1);
    edges[pos] = make_int2(ei[e], __float_as_int(ea[e]));
  }
}

// ---------------- fused GATv2 edge phase: wave per dst node ----------------
// Edge bounds + metadata are wave-uniform: readfirstlane scalarizes them so
// edge-list reads issue on the scalar pipe (s_load), freeing VMEM/VALU slots.
// leaky(s) = max(s, 0.2s) (2 ops). exp via exp2 with att pre-scaled by log2(e)
// (softmax ratios identical). xl/xr bf16: 8B/lane gathers, 4 edges in flight.
template <bool OUTBF>
__global__ __launch_bounds__(256) void gat_fused_kernel(
    const int* __restrict__ rowstart, const int2* __restrict__ edges,
    const unsigned short* __restrict__ xl, const unsigned short* __restrict__ xr,
    const float* __restrict__ we, const float* __restrict__ att,
    const float* __restrict__ bias, float* __restrict__ outf,
    unsigned short* __restrict__ outb) {
  int node = (blockIdx.x * 256 + threadIdx.x) >> 6;
  int lane = threadIdx.x & 63;
  int r0 = __builtin_amdgcn_readfirstlane(rowstart[node]);
  int r1 = __builtin_amdgcn_readfirstlane(rowstart[node + 1]);
  const uint2* xl2 = (const uint2*)xl;
  uint2 rp = ((const uint2*)xr)[(size_t)node * 64 + lane];
  float4 r = make_float4(bflo(rp.x), bfhi(rp.x), bflo(rp.y), bfhi(rp.y));
  float4 wv = ((const float4*)we)[lane];
  float4 at = ((const float4*)att)[lane];
  const float LOG2E = 1.442695040888963f;
  at.x *= LOG2E; at.y *= LOG2E; at.z *= LOG2E; at.w *= LOG2E;
  float4 acc = make_float4(0.f, 0.f, 0.f, 0.f);
  float denom = 0.f;

  auto edge_step = [&](float eav, uint2 p) {
    float4 a = make_float4(bflo(p.x), bfhi(p.x), bflo(p.y), bfhi(p.y));
    float s0 = a.x + (r.x + eav * wv.x);
    float s1 = a.y + (r.y + eav * wv.y);
    float s2 = a.z + (r.z + eav * wv.z);
    float s3 = a.w + (r.w + eav * wv.w);
    s0 = fmaxf(s0, 0.2f * s0);
    s1 = fmaxf(s1, 0.2f * s1);
    s2 = fmaxf(s2, 0.2f * s2);
    s3 = fmaxf(s3, 0.2f * s3);
    float p4 = (s0 * at.x + s1 * at.y) + (s2 * at.z + s3 * at.w);
#pragma unroll
    for (int off = 8; off; off >>= 1) p4 += __shfl_xor(p4, off, 16);
    float ex = exp2f(p4);
    denom += ex;
    acc.x += ex * a.x; acc.y += ex * a.y; acc.z += ex * a.z; acc.w += ex * a.w;
  };

  int i = r0;
  for (; i + 4 <= r1; i += 4) {           // 4 gathers in flight, scalar metadata
    int2 e0 = edges[i];
    int2 e1 = edges[i + 1];
    int2 e2 = edges[i + 2];
    int2 e3 = edges[i + 3];
    uint2 p0 = xl2[(size_t)e0.x * 64 + lane];
    uint2 p1 = xl2[(size_t)e1.x * 64 + lane];
    uint2 p2 = xl2[(size_t)e2.x * 64 + lane];
    uint2 p3 = xl2[(size_t)e3.x * 64 + lane];
    edge_step(__int_as_float(e0.y), p0);
    edge_step(__int_as_float(e1.y), p1);
    edge_step(__int_as_float(e2.y), p2);
    edge_step(__int_as_float(e3.y), p3);
  }
  for (; i < r1; ++i) {
    int2 e = edges[i];
    edge_step(__int_as_float(e.y), xl2[(size_t)e.x * 64 + lane]);
  }

  float inv = 1.f / (denom + 1e-16f);
  float4 bv = ((const float4*)bias)[lane];
  float4 o;
  o.x = fmaxf(acc.x * inv + bv.x, 0.f);
  o.y = fmaxf(acc.y * inv + bv.y, 0.f);
  o.z = fmaxf(acc.z * inv + bv.z, 0.f);
  o.w = fmaxf(acc.w * inv + bv.w, 0.f);
  if (OUTBF) {
    uint2 pk;
    pk.x = (unsigned)f2bf(o.x) | ((unsigned)f2bf(o.y) << 16);
    pk.y = (unsigned)f2bf(o.z) | ((unsigned)f2bf(o.w) << 16);
    ((uint2*)outb)[(size_t)node * 64 + lane] = pk;
  } else {
    ((float4*)outf)[(size_t)node * 64 + lane] = o;
  }
}

// ---------------- segment bounds via binary search (batch is sorted) ----------------
__global__ void seg_bounds_kernel(const int* __restrict__ batch, int* __restrict__ bounds) {
  int g = threadIdx.x;                 // 0..GG inclusive
  if (g > GG) return;
  int lo = 0, hi = NN;
  while (lo < hi) {
    int mid = (lo + hi) >> 1;
    if (batch[mid] < g) lo = mid + 1; else hi = mid;
  }
  bounds[g] = lo;
}

// ---------------- pooling: block = 64 nodes, 4 row-groups x 64 lanes (float4) ----
__global__ __launch_bounds__(256) void pool_kernel(
    const float* __restrict__ h, const int* __restrict__ batch,
    float* __restrict__ pool) {
  int rg = threadIdx.x >> 6;
  int lane = threadIdx.x & 63;
  int n0 = blockIdx.x * 64;
  const float4* h4 = (const float4*)h;
  float4 acc = make_float4(0.f, 0.f, 0.f, 0.f);
  int cur = -1;
#pragma unroll 4
  for (int i = 0; i < 16; ++i) {
    int n = n0 + rg + 4 * i;
    if (n >= NN) break;
    int b = batch[n];
    if (b != cur) {
      if (cur >= 0) {
        float* p = &pool[cur * 256 + lane * 4];
        atomicAdd(p + 0, acc.x); atomicAdd(p + 1, acc.y);
        atomicAdd(p + 2, acc.z); atomicAdd(p + 3, acc.w);
      }
      cur = b;
      acc = make_float4(0.f, 0.f, 0.f, 0.f);
    }
    float4 v = h4[(size_t)n * 64 + lane];
    acc.x += v.x; acc.y += v.y; acc.z += v.z; acc.w += v.w;
  }
  if (cur >= 0) {
    float* p = &pool[cur * 256 + lane * 4];
    atomicAdd(p + 0, acc.x); atomicAdd(p + 1, acc.y);
    atomicAdd(p + 2, acc.z); atomicAdd(p + 3, acc.w);
  }
}

// ---------------- final MLP: one block (128 thr) per graph ----------------
__global__ __launch_bounds__(128) void mlp_kernel(
    const float* __restrict__ pool, const int* __restrict__ bounds,
    const float* __restrict__ p1w, const float* __restrict__ p1b,
    const float* __restrict__ lng, const float* __restrict__ lnb,
    const float* __restrict__ p2w, const float* __restrict__ p2b,
    const float* __restrict__ hw, const float* __restrict__ hb,
    float* __restrict__ out) {
  __shared__ float sg[256];
  __shared__ float red[128];
  __shared__ float sz[128];
  __shared__ float s2[64];
  int b = blockIdx.x, tid = threadIdx.x;
  float cntf = (float)(bounds[b + 1] - bounds[b]);
  float invc = 1.f / fmaxf(cntf, 1.f);
  for (int i = tid; i < 256; i += 128) sg[i] = pool[b * 256 + i] * invc;
  __syncthreads();
  float z = p1b[tid];
  for (int k = 0; k < 256; ++k) z += sg[k] * p1w[k * 128 + tid];
  red[tid] = z; __syncthreads();
  for (int off = 64; off; off >>= 1) { if (tid < off) red[tid] += red[tid + off]; __syncthreads(); }
  float mu = red[0] * (1.f / 128.f);
  __syncthreads();
  float d = z - mu;
  red[tid] = d * d; __syncthreads();
  for (int off = 64; off; off >>= 1) { if (tid < off) red[tid] += red[tid + off]; __syncthreads(); }
  float var = red[0] * (1.f / 128.f);
  float zn = d * rsqrtf(var + 1e-5f) * lng[tid] + lnb[tid];
  sz[tid] = fmaxf(zn, 0.f);
  __syncthreads();
  if (tid < 64) {
    float a = p2b[tid];
    for (int k = 0; k < 128; ++k) a += sz[k] * p2w[k * 64 + tid];
    s2[tid] = fmaxf(a, 0.f);
  }
  __syncthreads();
  if (tid < 64) {
    float p = s2[tid] * hw[tid];
    for (int off = 32; off; off >>= 1) p += __shfl_down(p, off, 64);
    if (tid == 0) out[b] = p + hb[0];
  }
}

extern "C" void kernel_launch(void* const* d_in, const int* in_sizes, int n_in,
                              void* d_out, int out_size, void* d_ws, size_t ws_size,
                              hipStream_t stream) {
  const float* x      = (const float*)d_in[0];
  const int*   ei     = (const int*)d_in[1];
  const float* ea     = (const float*)d_in[2];
  const int*   batch  = (const int*)d_in[3];
  const float* enc_w  = (const float*)d_in[4];
  const float* enc_b  = (const float*)d_in[5];
  const float* g1_wl  = (const float*)d_in[6];
  const float* g1_bl  = (const float*)d_in[7];
  const float* g1_wr  = (const float*)d_in[8];
  const float* g1_we  = (const float*)d_in[9];
  const float* g1_att = (const float*)d_in[10];
  const float* g1_b   = (const float*)d_in[11];
  const float* g2_wl  = (const float*)d_in[12];
  const float* g2_bl  = (const float*)d_in[13];
  const float* g2_wr  = (const float*)d_in[14];
  const float* g2_we  = (const float*)d_in[15];
  const float* g2_att = (const float*)d_in[16];
  const float* g2_b   = (const float*)d_in[17];
  const float* p1_w   = (const float*)d_in[18];
  const float* p1_b   = (const float*)d_in[19];
  const float* ln_g   = (const float*)d_in[20];
  const float* ln_b   = (const float*)d_in[21];
  const float* p2_w   = (const float*)d_in[22];
  const float* p2_b   = (const float*)d_in[23];
  const float* head_w = (const float*)d_in[24];
  const float* head_b = (const float*)d_in[25];
  float* out = (float*)d_out;

  char* ws = (char*)d_ws;
  size_t off = 0;
  auto alloc = [&](size_t bytes) -> void* {
    void* p = ws + off;
    off = (off + bytes + 255) & ~(size_t)255;
    return p;
  };
  unsigned short* xl   = (unsigned short*)alloc((size_t)NN * HC * 2);
  unsigned short* xr   = (unsigned short*)alloc((size_t)NN * HC * 2);
  float* hbuf      = (float*)alloc((size_t)NN * HC * 4);
  unsigned short* h0   = (unsigned short*)alloc((size_t)NN * 64 * 2);
  unsigned short* hb16 = (unsigned short*)alloc((size_t)NN * HC * 2);
  unsigned short* wt1l = (unsigned short*)alloc((size_t)64 * 256 * 2);
  unsigned short* wt1r = (unsigned short*)alloc((size_t)64 * 256 * 2);
  unsigned short* wt2l = (unsigned short*)alloc((size_t)256 * 256 * 2);
  unsigned short* wt2r = (unsigned short*)alloc((size_t)256 * 256 * 2);
  float* pool      = (float*)alloc((size_t)GG * HC * 4);
  int*   deg       = (int*)alloc((size_t)NN * 4);
  int*   rowstart  = (int*)alloc((size_t)(NN + 1) * 4);
  int*   cursor    = (int*)alloc((size_t)NN * 4);
  int*   bsum      = (int*)alloc((size_t)NB * 4);
  int*   bpre      = (int*)alloc((size_t)NB * 4);
  int2*  edges     = (int2*)alloc((size_t)NE * 8);
  int*   bounds    = (int*)alloc((size_t)(GG + 1) * 4);

  hipMemsetAsync(deg, 0, (size_t)NN * 4, stream);
  hipMemsetAsync(pool, 0, (size_t)GG * HC * 4, stream);

  // encoder (bf16 out) + weight prep
  encoder_kernel<<<NN * 64 / 256, 256, 0, stream>>>(x, enc_w, enc_b, h0);
  wconv_kernel<<<64, 256, 0, stream>>>(g1_wl, 64, wt1l);
  wconv_kernel<<<64, 256, 0, stream>>>(g1_wr, 64, wt1r);
  wconv_kernel<<<256, 256, 0, stream>>>(g2_wl, 256, wt2l);
  wconv_kernel<<<256, 256, 0, stream>>>(g2_wr, 256, wt2r);

  // CSR build: degree -> hierarchical scan -> fill
  degree_kernel<<<(NE + 255) / 256, 256, 0, stream>>>(ei, deg);
  blocksum_kernel<<<NB, 256, 0, stream>>>(deg, bsum);
  blockscan_kernel<<<1, 256, 0, stream>>>(bsum, bpre, rowstart);
  rowstart_kernel<<<NB, 256, 0, stream>>>(deg, bpre, rowstart, cursor);
  fill_kernel<<<(NE + 255) / 256, 256, 0, stream>>>(ei, ea, cursor, edges);

  // graph segment bounds (batch is sorted)
  seg_bounds_kernel<<<1, GG + 1, 0, stream>>>(batch, bounds);

  dim3 mmg((NN + 127) / 128, 2);   // 391 x 2 blocks

  // ---- GAT layer 1 (K=64) ----
  matmul_mfma_kernel<64, true><<<mmg, 256, 0, stream>>>(h0, wt1l, g1_bl, xl, NN);
  matmul_mfma_kernel<64, false><<<mmg, 256, 0, stream>>>(h0, wt1r, nullptr, xr, NN);
  gat_fused_kernel<true><<<NN / 4, 256, 0, stream>>>(rowstart, edges,
                                                     xl, xr, g1_we, g1_att, g1_b,
                                                     nullptr, hb16);

  // ---- GAT layer 2 (K=256) ----
  matmul_mfma_kernel<256, true><<<mmg, 256, 0, stream>>>(hb16, wt2l, g2_bl, xl, NN);
  matmul_mfma_kernel<256, false><<<mmg, 256, 0, stream>>>(hb16, wt2r, nullptr, xr, NN);
  gat_fused_kernel<false><<<NN / 4, 256, 0, stream>>>(rowstart, edges,
                                                      xl, xr, g2_we, g2_att, g2_b,
                                                      hbuf, nullptr);

  // ---- pooling + MLP head ----
  pool_kernel<<<(NN + 63) / 64, 256, 0, stream>>>(hbuf, batch, pool);
  mlp_kernel<<<GG, 128, 0, stream>>>(pool, bounds, p1_w, p1_b, ln_g, ln_b,
                                     p2_w, p2_b, head_w, head_b, out);
}